// Round 7
// baseline (218.132 us; speedup 1.0000x reference)
//
#include <hip/hip_runtime.h>
#include <stdint.h>

typedef unsigned short u16;
typedef unsigned int u32;
typedef __attribute__((ext_vector_type(8))) short bf16x8;
typedef __attribute__((ext_vector_type(4))) float f32x4;
typedef __attribute__((ext_vector_type(4))) unsigned int u32x4;

__device__ __forceinline__ u16 f2b(float f) {
    union { float f; u32 u; } t; t.f = f;
    return (u16)((t.u + 0x7FFFu + ((t.u >> 16) & 1u)) >> 16);
}
__device__ __forceinline__ u32 pack2(float a, float b) {
    return (u32)f2b(a) | ((u32)f2b(b) << 16);
}
// single-instruction packed f32->bf16 (RNE)
__device__ __forceinline__ u32 cvtpk2(float lo, float hi) {
    u32 r;
    asm("v_cvt_pk_bf16_f32 %0, %1, %2" : "=v"(r) : "v"(lo), "v"(hi));
    return r;
}
// in-register lane-bit <-> reg-bit exchanges (gfx950)
__device__ __forceinline__ void permlane32_swap(u32& a, u32& b) {
    asm("v_permlane32_swap_b32 %0, %1" : "+v"(a), "+v"(b));
}
__device__ __forceinline__ void permlane16_swap(u32& a, u32& b) {
    asm("v_permlane16_swap_b32 %0, %1" : "+v"(a), "+v"(b));
}

// async global->LDS 16B copy: per-lane global addr, wave-uniform LDS base + lane*16
__device__ __forceinline__ void async_cp16(const u16* g, const u16* lds_base) {
    __builtin_amdgcn_global_load_lds(
        (const __attribute__((address_space(1))) void*)(uintptr_t)g,
        (__attribute__((address_space(3))) void*)(u32)(uintptr_t)lds_base,
        16, 0, 0);
}

// ---------------- fused fp32 -> bf16 cast (x + 4 weights, one launch) ----------------
__global__ void cast_all_kernel(const float* __restrict__ x,
                                const float* __restrict__ Wq, const float* __restrict__ Wk,
                                const float* __restrict__ Wv, const float* __restrict__ Wo,
                                u16* __restrict__ xb, u16* __restrict__ Wqb, u16* __restrict__ Wkb,
                                u16* __restrict__ Wvb, u16* __restrict__ Wob) {
    int i = blockIdx.x * blockDim.x + threadIdx.x;  // float4 index, total 2097152
    const float* s; u16* d; int off;
    if (i < 1048576) { s = x; d = xb; off = i; }
    else {
        int j = i - 1048576;
        int w = j >> 18; off = j & 262143;
        if (w == 0) { s = Wq; d = Wqb; }
        else if (w == 1) { s = Wk; d = Wkb; }
        else if (w == 2) { s = Wv; d = Wvb; }
        else { s = Wo; d = Wob; }
    }
    float4 f = ((const float4*)s)[off];
    ((uint2*)d)[off] = make_uint2(pack2(f.x, f.y), pack2(f.z, f.w));
}

// ---------------- fused QKV GEMM + STP projections + qe/ke/vT emission ----------------
// Round-4 body + XCD-aware decode (FETCH 69.8->33MB proven in round 5).
__global__ __launch_bounds__(256) void gemm_qkv_kernel(
    const u16* __restrict__ xb,
    const u16* __restrict__ Wq, const u16* __restrict__ Wk, const u16* __restrict__ Wv,
    const float* __restrict__ bq, const float* __restrict__ bk, const float* __restrict__ bv,
    const float* __restrict__ Wqs, const float* __restrict__ bqs,
    const float* __restrict__ Wks, const float* __restrict__ bks,
    const float* __restrict__ Wvs, const float* __restrict__ bvs,
    const float* __restrict__ temp_p,
    u16* __restrict__ qe, u16* __restrict__ ke, u16* __restrict__ vT,
    float4* __restrict__ k3b, float4* __restrict__ v3b)
{
    __shared__ __align__(16) u16 As[2 * 64 * 32];    // buf stride 2048 u16
    __shared__ __align__(16) u16 Bs[2 * 128 * 32];   // buf stride 4096 u16
    const int tid = threadIdx.x;
    const int lane = tid & 63, w = tid >> 6;
    const int wm = w >> 1, wn = w & 1;
    const int l15 = lane & 15, quad = lane >> 4;
    const int lin = blockIdx.x;                 // 1536 blocks
    const int M0 = (lin & 63) * 64;             // by -> XCD key
    const int N0 = ((lin >> 6) & 7) * 128;
    const int bz = lin >> 9;                    // 0,1,2

    const u16* W = (bz == 0) ? Wq : (bz == 1) ? Wk : Wv;
    const float* bias = (bz == 0) ? bq : (bz == 1) ? bk : bv;
    const float* Wst = (bz == 0) ? Wqs : (bz == 1) ? Wks : Wvs;
    const float* bst = (bz == 0) ? bqs : (bz == 1) ? bks : bvs;

    f32x4 acc[2][4];
#pragma unroll
    for (int i = 0; i < 2; i++)
#pragma unroll
        for (int j = 0; j < 4; j++) acc[i][j] = (f32x4){0.f, 0.f, 0.f, 0.f};

    int ra = tid >> 2, ca = ((tid & 3) ^ (ra & 3)) * 8;
    const u16* Aga = xb + (size_t)(M0 + ra) * 1024 + ca;
    const u16* Bg0 = W + (size_t)(N0 + ra) * 1024 + ca;
    const u16* Bg1 = W + (size_t)(N0 + ra + 64) * 1024 + ca;
    const int aoff = (w * 64) * 8;          // wave-uniform LDS unit offsets
    const int boff0 = (w * 64) * 8;
    const int boff1 = (256 + w * 64) * 8;

    // preheader: tile 0 -> buf 0
    async_cp16(Aga, As + aoff);
    async_cp16(Bg0, Bs + boff0);
    async_cp16(Bg1, Bs + boff1);
    __syncthreads();   // vmcnt drain: tile 0 resident

    for (int k0 = 0; k0 < 1024; k0 += 32) {
        const int buf = (k0 >> 5) & 1;
        const u16* Asr = As + buf * 2048;
        const u16* Bsr = Bs + buf * 4096;
        if (k0 + 32 < 1024) {   // issue next tile into idle buffer; flies under compute
            const int nb_ = buf ^ 1;
            async_cp16(Aga + k0 + 32, As + nb_ * 2048 + aoff);
            async_cp16(Bg0 + k0 + 32, Bs + nb_ * 4096 + boff0);
            async_cp16(Bg1 + k0 + 32, Bs + nb_ * 4096 + boff1);
        }

        bf16x8 af[2], bf[4];
#pragma unroll
        for (int mi = 0; mi < 2; mi++)
            af[mi] = *(const bf16x8*)(Asr + (wm * 32 + mi * 16 + l15) * 32 + ((quad ^ (l15 & 3)) * 8));
#pragma unroll
        for (int ni = 0; ni < 4; ni++)
            bf[ni] = *(const bf16x8*)(Bsr + (wn * 64 + ni * 16 + l15) * 32 + ((quad ^ (l15 & 3)) * 8));
#pragma unroll
        for (int mi = 0; mi < 2; mi++)
#pragma unroll
            for (int ni = 0; ni < 4; ni++)
                acc[mi][ni] = __builtin_amdgcn_mfma_f32_16x16x32_bf16(af[mi], bf[ni], acc[mi][ni], 0, 0, 0);

        __syncthreads();  // single barrier: buf read-done + next tile vmcnt drain
    }

    // ---- epilogue ----
    const float tau = temp_p[0] * 1.44269504088896f;
    const int nb = N0 + wn * 64;
    const int h = nb >> 6;
    float bias_v[4], wst_v[3][4];
#pragma unroll
    for (int ni = 0; ni < 4; ni++) {
        bias_v[ni] = bias[nb + ni * 16 + l15];
#pragma unroll
        for (int c = 0; c < 3; c++) wst_v[c][ni] = Wst[c * 64 + ni * 16 + l15];
    }
    const float bst0 = bst[0], bst1 = bst[1], bst2 = bst[2];

#pragma unroll
    for (int mi = 0; mi < 2; mi++) {
        int m0 = M0 + wm * 32 + mi * 16 + quad * 4;
        int b = m0 >> 11, t0 = m0 & 2047;
        float p0[4], p1[4], p2[4];
#pragma unroll
        for (int r = 0; r < 4; r++) {
            float a0 = 0.f, a1 = 0.f, a2 = 0.f;
#pragma unroll
            for (int ni = 0; ni < 4; ni++) {
                float v = acc[mi][ni][r] + bias_v[ni];
                a0 += v * wst_v[0][ni];
                a1 += v * wst_v[1][ni];
                a2 += v * wst_v[2][ni];
            }
#pragma unroll
            for (int off = 1; off < 16; off <<= 1) {
                a0 += __shfl_xor(a0, off);
                a1 += __shfl_xor(a1, off);
                a2 += __shfl_xor(a2, off);
            }
            p0[r] = a0 + bst0; p1[r] = a1 + bst1; p2[r] = a2 + bst2;
        }

        if (bz == 0) {
#pragma unroll
            for (int r = 0; r < 4; r++) {
                size_t row = (size_t)((b * 16 + h) * 2048 + (t0 + r));
                u16* qer = qe + row * 96;
#pragma unroll
                for (int ni = 0; ni < 4; ni++)
                    qer[ni * 16 + l15] = f2b((acc[mi][ni][r] + bias_v[ni]) * tau);
                if (l15 == 0) {
                    *(u32*)(qer + 64) = pack2(p0[r] * tau, p1[r] * tau);
                    *(u32*)(qer + 66) = (u32)f2b(p2[r] * tau);
                    uint2 z = make_uint2(0u, 0u);
#pragma unroll
                    for (int j = 68; j < 96; j += 4) *(uint2*)(qer + j) = z;
                }
            }
        } else if (bz == 1) {
#pragma unroll
            for (int r = 0; r < 4; r++) {
                size_t row = (size_t)((b * 16 + h) * 2048 + (t0 + r));
                u16* ker = ke + row * 96;
#pragma unroll
                for (int ni = 0; ni < 4; ni++)
                    ker[ni * 16 + l15] = f2b(acc[mi][ni][r] + bias_v[ni]);
                if (l15 == 0)
                    k3b[row] = make_float4(p0[r], p1[r], p2[r], 0.f);
            }
        } else {
#pragma unroll
            for (int ni = 0; ni < 4; ni++) {
                int hd = ni * 16 + l15;
                float v0 = acc[mi][ni][0] + bias_v[ni];
                float v1 = acc[mi][ni][1] + bias_v[ni];
                float v2 = acc[mi][ni][2] + bias_v[ni];
                float v3 = acc[mi][ni][3] + bias_v[ni];
                *(uint2*)(vT + ((size_t)((b * 16 + h) * 64 + hd)) * 2048 + t0) =
                    make_uint2(pack2(v0, v1), pack2(v2, v3));
            }
            if (l15 == 0) {
#pragma unroll
                for (int r = 0; r < 4; r++) {
                    size_t row = (size_t)((b * 16 + h) * 2048 + (t0 + r));
                    v3b[row] = make_float4(p0[r], p1[r], p2[r], 0.f);
                }
            }
        }
    }
}

// ---------------- finish: ke[64:67] = cross(k3,v3), ke[67:96] = 0 ----------------
__global__ void finish_ext_kernel(const float4* __restrict__ k3b, const float4* __restrict__ v3b,
                                  u16* __restrict__ ke)
{
    int row = blockIdx.x * blockDim.x + threadIdx.x;
    if (row >= 2 * 16 * 2048) return;
    float4 k3 = k3b[row];
    float4 v3 = v3b[row];
    float c0 = k3.y * v3.z - k3.z * v3.y;
    float c1 = k3.z * v3.x - k3.x * v3.z;
    float c2 = k3.x * v3.y - k3.y * v3.x;
    u16* ker = ke + (size_t)row * 96;
    *(u32*)(ker + 64) = pack2(c0, c1);
    *(u32*)(ker + 66) = (u32)f2b(c2);
    uint2 z = make_uint2(0u, 0u);
#pragma unroll
    for (int j = 68; j < 96; j += 4) *(uint2*)(ker + j) = z;
}

// ---------------- out-projection GEMM: 64x128 tiles, double-buffered async ----------
// XCD-aware linear decode (same-A blocks -> same XCD), proven in round 5.
__global__ __launch_bounds__(256) void gemm_out_kernel(
    const u16* __restrict__ ao, const u16* __restrict__ Wo, const float* __restrict__ bo,
    float* __restrict__ out)
{
    __shared__ __align__(16) u16 As[2 * 64 * 32];
    __shared__ __align__(16) u16 Bs[2 * 128 * 32];
    const int tid = threadIdx.x;
    const int lane = tid & 63, w = tid >> 6;
    const int wm = w >> 1, wn = w & 1;
    const int l15 = lane & 15, quad = lane >> 4;
    const int lin = blockIdx.x;
    const int M0 = (lin & 63) * 64;
    const int N0 = (lin >> 6) * 128;

    f32x4 acc[2][4];
#pragma unroll
    for (int i = 0; i < 2; i++)
#pragma unroll
        for (int j = 0; j < 4; j++) acc[i][j] = (f32x4){0.f, 0.f, 0.f, 0.f};

    int ra = tid >> 2, ca = ((tid & 3) ^ (ra & 3)) * 8;
    const u16* Aga = ao + (size_t)(M0 + ra) * 1024 + ca;
    const u16* Bg0 = Wo + (size_t)(N0 + ra) * 1024 + ca;
    const u16* Bg1 = Wo + (size_t)(N0 + ra + 64) * 1024 + ca;
    const int aoff = (w * 64) * 8;
    const int boff0 = (w * 64) * 8;
    const int boff1 = (256 + w * 64) * 8;

    async_cp16(Aga, As + aoff);
    async_cp16(Bg0, Bs + boff0);
    async_cp16(Bg1, Bs + boff1);
    __syncthreads();

    for (int k0 = 0; k0 < 1024; k0 += 32) {
        const int buf = (k0 >> 5) & 1;
        const u16* Asr = As + buf * 2048;
        const u16* Bsr = Bs + buf * 4096;
        if (k0 + 32 < 1024) {
            const int nb_ = buf ^ 1;
            async_cp16(Aga + k0 + 32, As + nb_ * 2048 + aoff);
            async_cp16(Bg0 + k0 + 32, Bs + nb_ * 4096 + boff0);
            async_cp16(Bg1 + k0 + 32, Bs + nb_ * 4096 + boff1);
        }

        bf16x8 af[2], bf[4];
#pragma unroll
        for (int mi = 0; mi < 2; mi++)
            af[mi] = *(const bf16x8*)(Asr + (wm * 32 + mi * 16 + l15) * 32 + ((quad ^ (l15 & 3)) * 8));
#pragma unroll
        for (int ni = 0; ni < 4; ni++)
            bf[ni] = *(const bf16x8*)(Bsr + (wn * 64 + ni * 16 + l15) * 32 + ((quad ^ (l15 & 3)) * 8));
#pragma unroll
        for (int mi = 0; mi < 2; mi++)
#pragma unroll
            for (int ni = 0; ni < 4; ni++)
                acc[mi][ni] = __builtin_amdgcn_mfma_f32_16x16x32_bf16(af[mi], bf[ni], acc[mi][ni], 0, 0, 0);

        __syncthreads();
    }

#pragma unroll
    for (int mi = 0; mi < 2; mi++)
#pragma unroll
        for (int ni = 0; ni < 4; ni++) {
            int n = N0 + wn * 64 + ni * 16 + l15;
            float bias_n = bo[n];
            int m0 = M0 + wm * 32 + mi * 16 + quad * 4;
#pragma unroll
            for (int r = 0; r < 4; r++)
                out[(size_t)(m0 + r) * 1024 + n] = acc[mi][ni][r] + bias_n;
        }
}

// ---------------- flash attention ----------------
// Round-16 (vs round-4 body, structure unchanged):
//  * bh-XCD-affine decode: bh = (lin&7) + 8*((lin>>3)&3), qt = lin>>5 -> all 16
//    q-blocks of one bh get lin%8 = bh%8 -> ONE XCD. Each XCD's 4 bh's K/V =
//    2.5MB fits its 4MB L2 -> K/V HBM-fetched once (was ~3x: FETCH 88MB, ideal 33).
//  * K staging OOB clamp: source chunks 12..15 read past the 96-u16 row (25% K
//    over-fetch). Their LDS positions are provably never read -> redirect source
//    to chunk c-8 (in-row, duplicates another lane's cacheline -> free).
__global__ __launch_bounds__(256, 2) void attn_kernel(
    const u16* __restrict__ qe, const u16* __restrict__ ke, const u16* __restrict__ vT,
    u16* __restrict__ out)
{
    __shared__ __align__(16) u16 smem[24576];   // 48 KB
    u16* const KsA = smem;            // 2 x 8192 u16: K tiles [64 rows][128 u16]
    u16* const VtA = smem + 16384;    // 2 x 4096 u16: V tiles [64 d][64 u16]

    const int tid = threadIdx.x;
    const int lane = tid & 63, w = tid >> 6;
    const int kw = w & 1, qw = w >> 1;
    const int l15 = lane & 15, quad = lane >> 4;
    const int lsw = l15 & 7;
    const int lin = blockIdx.x;                       // 512 blocks
    const int bh = (lin & 7) + ((lin >> 3) & 3) * 8;  // lin%8 == bh%8 -> XCD affinity
    const int q0 = (lin >> 5) * 128;

    const u16* qeb = qe + (size_t)bh * 2048 * 96;
    const u16* keb = ke + (size_t)bh * 2048 * 96;
    const u16* vTb = vT + (size_t)bh * 64 * 2048;

    // --- pre-swizzled staging source offsets; wave w owns tile rows [16w,16w+16) ---
    size_t koff[4];
#pragma unroll
    for (int j = 0; j < 4; j++) {
        int r = w * 16 + j * 4 + (lane >> 4);
        int c = (lane & 15) ^ (r & 7);
        if (c >= 12) c -= 8;   // OOB clamp: position never read; keep fetch in-row
        koff[j] = (size_t)r * 96 + (size_t)(c * 8);
    }
    size_t voff[2];
#pragma unroll
    for (int j = 0; j < 2; j++) {
        int r = w * 16 + j * 8 + (lane >> 3);
        voff[j] = (size_t)r * 2048 + (size_t)((((lane & 7) ^ (r & 7)) * 8));
    }

    // prologue: stage tile 0 into buf 0 (flies under the Q-fragment loads below)
#pragma unroll
    for (int j = 0; j < 4; j++) async_cp16(keb + koff[j], KsA + w * 2048 + j * 512);
#pragma unroll
    for (int j = 0; j < 2; j++) async_cp16(vTb + voff[j], VtA + w * 1024 + j * 512);

    bf16x8 bq[4][3];
#pragma unroll
    for (int s = 0; s < 4; s++) {
        const u16* qrow = qeb + (size_t)(q0 + qw * 64 + s * 16 + l15) * 96;
#pragma unroll
        for (int ks = 0; ks < 3; ks++) bq[s][ks] = *(const bf16x8*)(qrow + ks * 32 + quad * 8);
    }

    f32x4 O[4][4];
    float l_part[4];
#pragma unroll
    for (int s = 0; s < 4; s++) {
        l_part[s] = 0.f;
#pragma unroll
        for (int dt = 0; dt < 4; dt++) O[s][dt] = (f32x4){0.f, 0.f, 0.f, 0.f};
    }

    __syncthreads();   // tile 0 resident (vmcnt drained by barrier)

    for (int kb = 0; kb < 2048; kb += 64) {
        const int buf = (kb >> 6) & 1;
        const u16* Ks = KsA + buf * 8192;
        const u16* Vt = VtA + buf * 4096;

        if (kb + 64 < 2048) {   // prefetch next tile into idle buffer (async, drained at barrier)
            u16* Ksn = KsA + (buf ^ 1) * 8192;
            u16* Vtn = VtA + (buf ^ 1) * 4096;
            const size_t kb96 = (size_t)(kb + 64) * 96;
#pragma unroll
            for (int j = 0; j < 4; j++) async_cp16(keb + kb96 + koff[j], Ksn + w * 2048 + j * 512);
#pragma unroll
            for (int j = 0; j < 2; j++) async_cp16(vTb + (size_t)(kb + 64) + voff[j], Vtn + w * 1024 + j * 512);
        }

        f32x4 S[4][2];
#pragma unroll
        for (int s = 0; s < 4; s++)
#pragma unroll
            for (int nt = 0; nt < 2; nt++) S[s][nt] = (f32x4){0.f, 0.f, 0.f, 0.f};

        __builtin_amdgcn_s_setprio(1);
#pragma unroll
        for (int ks = 0; ks < 3; ks++) {
            bf16x8 ak[2];
#pragma unroll
            for (int nt = 0; nt < 2; nt++)
                ak[nt] = *(const bf16x8*)(Ks + (kw * 32 + nt * 16 + l15) * 128 + (((ks * 4 + quad) ^ lsw) & 15) * 8);
#pragma unroll
            for (int s = 0; s < 4; s++)
#pragma unroll
                for (int nt = 0; nt < 2; nt++)
                    S[s][nt] = __builtin_amdgcn_mfma_f32_16x16x32_bf16(ak[nt], bq[s][ks], S[s][nt], 0, 0, 0);
        }
        __builtin_amdgcn_s_setprio(0);

        // V fragments for PV
        bf16x8 av[4];
#pragma unroll
        for (int dt = 0; dt < 4; dt++)
            av[dt] = *(const bf16x8*)(Vt + (dt * 16 + l15) * 64 + (((kw * 4 + quad) ^ lsw) & 7) * 8);

        // per-s: exp + pack + in-register redistribution -> 4 PV MFMAs
#pragma unroll
        for (int s = 0; s < 4; s++) {
            float sum = 0.f;
#pragma unroll
            for (int nt = 0; nt < 2; nt++)
#pragma unroll
                for (int r = 0; r < 4; r++) {
                    float p = __builtin_amdgcn_exp2f(S[s][nt][r]);
                    S[s][nt][r] = p;
                    sum += p;
                }
            l_part[s] += sum;
            u32 a0 = cvtpk2(S[s][0][0], S[s][0][1]);   // U[nt=0][p=0]
            u32 b0 = cvtpk2(S[s][1][0], S[s][1][1]);   // U[1][0]
            u32 a1 = cvtpk2(S[s][0][2], S[s][0][3]);   // U[0][1]
            u32 b1 = cvtpk2(S[s][1][2], S[s][1][3]);   // U[1][1]
            permlane32_swap(a0, b0);   // reg-bit nt <-> lane-bit5
            permlane32_swap(a1, b1);
            permlane16_swap(a0, b0);   // reg-bit <-> lane-bit4
            permlane16_swap(a1, b1);
            bf16x8 pv = __builtin_bit_cast(bf16x8, (u32x4){a0, a1, b0, b1});
            __builtin_amdgcn_s_setprio(1);
#pragma unroll
            for (int dt = 0; dt < 4; dt++)
                O[s][dt] = __builtin_amdgcn_mfma_f32_16x16x32_bf16(av[dt], pv, O[s][dt], 0, 0, 0);
            __builtin_amdgcn_s_setprio(0);
        }

        __syncthreads();  // buf read-done + prefetch vmcnt drain
    }

    float* const Ored = (float*)smem;                 // 128 x 68 floats = 34816 B
    float* const Lr = (float*)(smem + 17664);         // byte 35328, 512 B
    if (kw == 1) {
#pragma unroll
        for (int s = 0; s < 4; s++) {
            float l = l_part[s];
            l += __shfl_xor(l, 16);
            l += __shfl_xor(l, 32);
            if (lane < 16) Lr[qw * 64 + s * 16 + l15] = l;
            int qrow = qw * 64 + s * 16 + l15;
#pragma unroll
            for (int dt = 0; dt < 4; dt++) {
                int dc = dt ^ (l15 & 3);
                *(float4*)(Ored + qrow * 68 + dc * 16 + quad * 4) =
                    make_float4(O[s][dt][0], O[s][dt][1], O[s][dt][2], O[s][dt][3]);
            }
        }
    }
    __syncthreads();
    if (kw == 0) {
        const int b = bh >> 4, h = bh & 15;
#pragma unroll
        for (int s = 0; s < 4; s++) {
            float l = l_part[s];
            l += __shfl_xor(l, 16);
            l += __shfl_xor(l, 32);
            int qrow = qw * 64 + s * 16 + l15;
            l += Lr[qrow];
            float linv = 1.0f / l;
            int tq = q0 + qrow;
#pragma unroll
            for (int dt = 0; dt < 4; dt++) {
                int dc = dt ^ (l15 & 3);
                float4 o2 = *(const float4*)(Ored + qrow * 68 + dc * 16 + quad * 4);
                int d = h * 64 + dt * 16 + quad * 4;
                *(uint2*)(out + (size_t)(b * 2048 + tq) * 1024 + d) =
                    make_uint2(cvtpk2((O[s][dt][0] + o2.x) * linv, (O[s][dt][1] + o2.y) * linv),
                               cvtpk2((O[s][dt][2] + o2.z) * linv, (O[s][dt][3] + o2.w) * linv));
            }
        }
    }
}

// ---------------- launch ----------------
extern "C" void kernel_launch(void* const* d_in, const int* in_sizes, int n_in,
                              void* d_out, int out_size, void* d_ws, size_t ws_size,
                              hipStream_t stream)
{
    (void)in_sizes; (void)n_in; (void)out_size; (void)ws_size;
    const float* x   = (const float*)d_in[0];
    const float* Wq  = (const float*)d_in[1];
    const float* bq  = (const float*)d_in[2];
    const float* Wk  = (const float*)d_in[3];
    const float* bk  = (const float*)d_in[4];
    const float* Wv  = (const float*)d_in[5];
    const float* bv  = (const float*)d_in[6];
    const float* Wo  = (const float*)d_in[7];
    const float* bo  = (const float*)d_in[8];
    const float* Wqs = (const float*)d_in[9];
    const float* bqs = (const float*)d_in[10];
    const float* Wks = (const float*)d_in[11];
    const float* bks = (const float*)d_in[12];
    const float* Wvs = (const float*)d_in[13];
    const float* bvs = (const float*)d_in[14];
    const float* temp = (const float*)d_in[15];

    char* ws = (char*)d_ws;
    u16* xb  = (u16*)(ws);                  // 8 MB
    u16* Wqb = (u16*)(ws + 8388608);        // 2 MB
    u16* Wkb = (u16*)(ws + 10485760);       // 2 MB
    u16* Wvb = (u16*)(ws + 12582912);       // 2 MB
    u16* Wob = (u16*)(ws + 14680064);       // 2 MB
    u16* qeb = (u16*)(ws + 16777216);       // 12 MB [B,H,T,96]
    u16* keb = (u16*)(ws + 29360128);       // 12 MB
    u16* vTb = (u16*)(ws + 41943040);       // 8 MB  [B,H,64,T]
    float4* k3b = (float4*)(ws + 50331648); // 1 MB  [B*H*T]
    float4* v3b = (float4*)(ws + 51380224); // 1 MB
    u16* aob = (u16*)(ws + 52428800);       // 8 MB  [B,T,D]

    cast_all_kernel<<<8192, 256, 0, stream>>>(x, Wq, Wk, Wv, Wo, xb, Wqb, Wkb, Wvb, Wob);
    gemm_qkv_kernel<<<1536, 256, 0, stream>>>(
        xb, Wqb, Wkb, Wvb, bq, bk, bv, Wqs, bqs, Wks, bks, Wvs, bvs, temp,
        qeb, keb, vTb, k3b, v3b);
    finish_ext_kernel<<<256, 256, 0, stream>>>(k3b, v3b, keb);
    attn_kernel<<<512, 256, 0, stream>>>(qeb, keb, vTb, aob);
    gemm_out_kernel<<<512, 256, 0, stream>>>(aob, Wob, bo, (float*)d_out);
}

// Round 8
// 210.994 us; speedup vs baseline: 1.0338x; 1.0338x over previous
//
#include <hip/hip_runtime.h>
#include <stdint.h>

typedef unsigned short u16;
typedef unsigned int u32;
typedef __attribute__((ext_vector_type(8))) short bf16x8;
typedef __attribute__((ext_vector_type(4))) float f32x4;
typedef __attribute__((ext_vector_type(4))) unsigned int u32x4;

__device__ __forceinline__ u16 f2b(float f) {
    union { float f; u32 u; } t; t.f = f;
    return (u16)((t.u + 0x7FFFu + ((t.u >> 16) & 1u)) >> 16);
}
__device__ __forceinline__ u32 pack2(float a, float b) {
    return (u32)f2b(a) | ((u32)f2b(b) << 16);
}
// single-instruction packed f32->bf16 (RNE)
__device__ __forceinline__ u32 cvtpk2(float lo, float hi) {
    u32 r;
    asm("v_cvt_pk_bf16_f32 %0, %1, %2" : "=v"(r) : "v"(lo), "v"(hi));
    return r;
}
// in-register lane-bit <-> reg-bit exchanges (gfx950)
__device__ __forceinline__ void permlane32_swap(u32& a, u32& b) {
    asm("v_permlane32_swap_b32 %0, %1" : "+v"(a), "+v"(b));
}
__device__ __forceinline__ void permlane16_swap(u32& a, u32& b) {
    asm("v_permlane16_swap_b32 %0, %1" : "+v"(a), "+v"(b));
}

// async global->LDS 16B copy: per-lane global addr, wave-uniform LDS base + lane*16
__device__ __forceinline__ void async_cp16(const u16* g, const u16* lds_base) {
    __builtin_amdgcn_global_load_lds(
        (const __attribute__((address_space(1))) void*)(uintptr_t)g,
        (__attribute__((address_space(3))) void*)(u32)(uintptr_t)lds_base,
        16, 0, 0);
}

// ---------------- fused fp32 -> bf16 cast (x + 4 weights, one launch) ----------------
__global__ void cast_all_kernel(const float* __restrict__ x,
                                const float* __restrict__ Wq, const float* __restrict__ Wk,
                                const float* __restrict__ Wv, const float* __restrict__ Wo,
                                u16* __restrict__ xb, u16* __restrict__ Wqb, u16* __restrict__ Wkb,
                                u16* __restrict__ Wvb, u16* __restrict__ Wob) {
    int i = blockIdx.x * blockDim.x + threadIdx.x;  // float4 index, total 2097152
    const float* s; u16* d; int off;
    if (i < 1048576) { s = x; d = xb; off = i; }
    else {
        int j = i - 1048576;
        int w = j >> 18; off = j & 262143;
        if (w == 0) { s = Wq; d = Wqb; }
        else if (w == 1) { s = Wk; d = Wkb; }
        else if (w == 2) { s = Wv; d = Wvb; }
        else { s = Wo; d = Wob; }
    }
    float4 f = ((const float4*)s)[off];
    ((uint2*)d)[off] = make_uint2(pack2(f.x, f.y), pack2(f.z, f.w));
}

// ---------------- fused QKV GEMM + STP projections + qe/ke/vT emission ----------------
// Round-17: 128x128 tile (BK=32). Per-barrier MFMA work doubles (16/wave vs 8),
// A-staging bytes per FLOP halve. Guide's measured tile-space for this exact
// 2-barrier structure: 64-tile=343 TF vs 128^2=912 TF. LDS 32KB (2x16 dbuf),
// acc[4][4]=64 VGPR. Grid 768 = 32 Mt x 8 Nt x 3 z, XCD decode Mt=lin&31
// (same-A blocks -> same XCD, preserves round-5's proven FETCH win).
__global__ __launch_bounds__(256) void gemm_qkv_kernel(
    const u16* __restrict__ xb,
    const u16* __restrict__ Wq, const u16* __restrict__ Wk, const u16* __restrict__ Wv,
    const float* __restrict__ bq, const float* __restrict__ bk, const float* __restrict__ bv,
    const float* __restrict__ Wqs, const float* __restrict__ bqs,
    const float* __restrict__ Wks, const float* __restrict__ bks,
    const float* __restrict__ Wvs, const float* __restrict__ bvs,
    const float* __restrict__ temp_p,
    u16* __restrict__ qe, u16* __restrict__ ke, u16* __restrict__ vT,
    float4* __restrict__ k3b, float4* __restrict__ v3b)
{
    __shared__ __align__(16) u16 As[2 * 128 * 32];   // 16 KB, buf stride 4096 u16
    __shared__ __align__(16) u16 Bs[2 * 128 * 32];   // 16 KB
    const int tid = threadIdx.x;
    const int lane = tid & 63, w = tid >> 6;
    const int wm = w >> 1, wn = w & 1;
    const int l15 = lane & 15, quad = lane >> 4;
    const int lin = blockIdx.x;                 // 768 blocks
    const int M0 = (lin & 31) * 128;            // Mt -> XCD key (lin%8 = Mt%8)
    const int N0 = ((lin >> 5) & 7) * 128;
    const int bz = lin >> 8;                    // 0,1,2

    const u16* W = (bz == 0) ? Wq : (bz == 1) ? Wk : Wv;
    const float* bias = (bz == 0) ? bq : (bz == 1) ? bk : bv;
    const float* Wst = (bz == 0) ? Wqs : (bz == 1) ? Wks : Wvs;
    const float* bst = (bz == 0) ? bqs : (bz == 1) ? bks : bvs;

    f32x4 acc[4][4];
#pragma unroll
    for (int i = 0; i < 4; i++)
#pragma unroll
        for (int j = 0; j < 4; j++) acc[i][j] = (f32x4){0.f, 0.f, 0.f, 0.f};

    // staging: wave w owns tile rows [32w, 32w+32); 2 issues each for A and B.
    // lane -> row 32w + 16j + (lane>>2), chunk pos lane&3, src col (pos^(row&3))*8
    const int ca2 = ((lane & 3) ^ ((lane >> 2) & 3)) * 8;
    const u16* Ag = xb + (size_t)(M0 + w * 32 + (lane >> 2)) * 1024 + ca2;
    const u16* Bg = W + (size_t)(N0 + w * 32 + (lane >> 2)) * 1024 + ca2;
    const int dst0 = w * 1024;            // u16 units within a buf
    const int dst1 = w * 1024 + 512;

    // preheader: tile 0 -> buf 0
    async_cp16(Ag, As + dst0);
    async_cp16(Ag + 16 * 1024, As + dst1);
    async_cp16(Bg, Bs + dst0);
    async_cp16(Bg + 16 * 1024, Bs + dst1);
    __syncthreads();   // vmcnt drain: tile 0 resident

    for (int k0 = 0; k0 < 1024; k0 += 32) {
        const int buf = (k0 >> 5) & 1;
        const u16* Asr = As + buf * 4096;
        const u16* Bsr = Bs + buf * 4096;
        if (k0 + 32 < 1024) {   // issue next tile into idle buffer; flies under compute
            const int nb_ = (buf ^ 1) * 4096;
            async_cp16(Ag + k0 + 32, As + nb_ + dst0);
            async_cp16(Ag + 16 * 1024 + k0 + 32, As + nb_ + dst1);
            async_cp16(Bg + k0 + 32, Bs + nb_ + dst0);
            async_cp16(Bg + 16 * 1024 + k0 + 32, Bs + nb_ + dst1);
        }

        bf16x8 af[4], bf[4];
#pragma unroll
        for (int mi = 0; mi < 4; mi++)
            af[mi] = *(const bf16x8*)(Asr + (wm * 64 + mi * 16 + l15) * 32 + ((quad ^ (l15 & 3)) * 8));
#pragma unroll
        for (int ni = 0; ni < 4; ni++)
            bf[ni] = *(const bf16x8*)(Bsr + (wn * 64 + ni * 16 + l15) * 32 + ((quad ^ (l15 & 3)) * 8));
#pragma unroll
        for (int mi = 0; mi < 4; mi++)
#pragma unroll
            for (int ni = 0; ni < 4; ni++)
                acc[mi][ni] = __builtin_amdgcn_mfma_f32_16x16x32_bf16(af[mi], bf[ni], acc[mi][ni], 0, 0, 0);

        __syncthreads();  // single barrier: buf read-done + next tile vmcnt drain
    }

    // ---- epilogue ----
    const float tau = temp_p[0] * 1.44269504088896f;
    const int nb = N0 + wn * 64;
    const int h = nb >> 6;
    float bias_v[4], wst_v[3][4];
#pragma unroll
    for (int ni = 0; ni < 4; ni++) {
        bias_v[ni] = bias[nb + ni * 16 + l15];
#pragma unroll
        for (int c = 0; c < 3; c++) wst_v[c][ni] = Wst[c * 64 + ni * 16 + l15];
    }
    const float bst0 = bst[0], bst1 = bst[1], bst2 = bst[2];

#pragma unroll
    for (int mi = 0; mi < 4; mi++) {
        int m0 = M0 + wm * 64 + mi * 16 + quad * 4;
        int b = m0 >> 11, t0 = m0 & 2047;
        float p0[4], p1[4], p2[4];
#pragma unroll
        for (int r = 0; r < 4; r++) {
            float a0 = 0.f, a1 = 0.f, a2 = 0.f;
#pragma unroll
            for (int ni = 0; ni < 4; ni++) {
                float v = acc[mi][ni][r] + bias_v[ni];
                a0 += v * wst_v[0][ni];
                a1 += v * wst_v[1][ni];
                a2 += v * wst_v[2][ni];
            }
#pragma unroll
            for (int off = 1; off < 16; off <<= 1) {
                a0 += __shfl_xor(a0, off);
                a1 += __shfl_xor(a1, off);
                a2 += __shfl_xor(a2, off);
            }
            p0[r] = a0 + bst0; p1[r] = a1 + bst1; p2[r] = a2 + bst2;
        }

        if (bz == 0) {
#pragma unroll
            for (int r = 0; r < 4; r++) {
                size_t row = (size_t)((b * 16 + h) * 2048 + (t0 + r));
                u16* qer = qe + row * 96;
#pragma unroll
                for (int ni = 0; ni < 4; ni++)
                    qer[ni * 16 + l15] = f2b((acc[mi][ni][r] + bias_v[ni]) * tau);
                if (l15 == 0) {
                    *(u32*)(qer + 64) = pack2(p0[r] * tau, p1[r] * tau);
                    *(u32*)(qer + 66) = (u32)f2b(p2[r] * tau);
                    uint2 z = make_uint2(0u, 0u);
#pragma unroll
                    for (int j = 68; j < 96; j += 4) *(uint2*)(qer + j) = z;
                }
            }
        } else if (bz == 1) {
#pragma unroll
            for (int r = 0; r < 4; r++) {
                size_t row = (size_t)((b * 16 + h) * 2048 + (t0 + r));
                u16* ker = ke + row * 96;
#pragma unroll
                for (int ni = 0; ni < 4; ni++)
                    ker[ni * 16 + l15] = f2b(acc[mi][ni][r] + bias_v[ni]);
                if (l15 == 0)
                    k3b[row] = make_float4(p0[r], p1[r], p2[r], 0.f);
            }
        } else {
#pragma unroll
            for (int ni = 0; ni < 4; ni++) {
                int hd = ni * 16 + l15;
                float v0 = acc[mi][ni][0] + bias_v[ni];
                float v1 = acc[mi][ni][1] + bias_v[ni];
                float v2 = acc[mi][ni][2] + bias_v[ni];
                float v3 = acc[mi][ni][3] + bias_v[ni];
                *(uint2*)(vT + ((size_t)((b * 16 + h) * 64 + hd)) * 2048 + t0) =
                    make_uint2(pack2(v0, v1), pack2(v2, v3));
            }
            if (l15 == 0) {
#pragma unroll
                for (int r = 0; r < 4; r++) {
                    size_t row = (size_t)((b * 16 + h) * 2048 + (t0 + r));
                    v3b[row] = make_float4(p0[r], p1[r], p2[r], 0.f);
                }
            }
        }
    }
}

// ---------------- finish: ke[64:67] = cross(k3,v3), ke[67:96] = 0 ----------------
__global__ void finish_ext_kernel(const float4* __restrict__ k3b, const float4* __restrict__ v3b,
                                  u16* __restrict__ ke)
{
    int row = blockIdx.x * blockDim.x + threadIdx.x;
    if (row >= 2 * 16 * 2048) return;
    float4 k3 = k3b[row];
    float4 v3 = v3b[row];
    float c0 = k3.y * v3.z - k3.z * v3.y;
    float c1 = k3.z * v3.x - k3.x * v3.z;
    float c2 = k3.x * v3.y - k3.y * v3.x;
    u16* ker = ke + (size_t)row * 96;
    *(u32*)(ker + 64) = pack2(c0, c1);
    *(u32*)(ker + 66) = (u32)f2b(c2);
    uint2 z = make_uint2(0u, 0u);
#pragma unroll
    for (int j = 68; j < 96; j += 4) *(uint2*)(ker + j) = z;
}

// ---------------- out-projection GEMM: 64x128 tiles, double-buffered async ----------
// XCD-aware linear decode (same-A blocks -> same XCD), proven in round 5.
__global__ __launch_bounds__(256) void gemm_out_kernel(
    const u16* __restrict__ ao, const u16* __restrict__ Wo, const float* __restrict__ bo,
    float* __restrict__ out)
{
    __shared__ __align__(16) u16 As[2 * 64 * 32];
    __shared__ __align__(16) u16 Bs[2 * 128 * 32];
    const int tid = threadIdx.x;
    const int lane = tid & 63, w = tid >> 6;
    const int wm = w >> 1, wn = w & 1;
    const int l15 = lane & 15, quad = lane >> 4;
    const int lin = blockIdx.x;
    const int M0 = (lin & 63) * 64;
    const int N0 = (lin >> 6) * 128;

    f32x4 acc[2][4];
#pragma unroll
    for (int i = 0; i < 2; i++)
#pragma unroll
        for (int j = 0; j < 4; j++) acc[i][j] = (f32x4){0.f, 0.f, 0.f, 0.f};

    int ra = tid >> 2, ca = ((tid & 3) ^ (ra & 3)) * 8;
    const u16* Aga = ao + (size_t)(M0 + ra) * 1024 + ca;
    const u16* Bg0 = Wo + (size_t)(N0 + ra) * 1024 + ca;
    const u16* Bg1 = Wo + (size_t)(N0 + ra + 64) * 1024 + ca;
    const int aoff = (w * 64) * 8;
    const int boff0 = (w * 64) * 8;
    const int boff1 = (256 + w * 64) * 8;

    async_cp16(Aga, As + aoff);
    async_cp16(Bg0, Bs + boff0);
    async_cp16(Bg1, Bs + boff1);
    __syncthreads();

    for (int k0 = 0; k0 < 1024; k0 += 32) {
        const int buf = (k0 >> 5) & 1;
        const u16* Asr = As + buf * 2048;
        const u16* Bsr = Bs + buf * 4096;
        if (k0 + 32 < 1024) {
            const int nb_ = buf ^ 1;
            async_cp16(Aga + k0 + 32, As + nb_ * 2048 + aoff);
            async_cp16(Bg0 + k0 + 32, Bs + nb_ * 4096 + boff0);
            async_cp16(Bg1 + k0 + 32, Bs + nb_ * 4096 + boff1);
        }

        bf16x8 af[2], bf[4];
#pragma unroll
        for (int mi = 0; mi < 2; mi++)
            af[mi] = *(const bf16x8*)(Asr + (wm * 32 + mi * 16 + l15) * 32 + ((quad ^ (l15 & 3)) * 8));
#pragma unroll
        for (int ni = 0; ni < 4; ni++)
            bf[ni] = *(const bf16x8*)(Bsr + (wn * 64 + ni * 16 + l15) * 32 + ((quad ^ (l15 & 3)) * 8));
#pragma unroll
        for (int mi = 0; mi < 2; mi++)
#pragma unroll
            for (int ni = 0; ni < 4; ni++)
                acc[mi][ni] = __builtin_amdgcn_mfma_f32_16x16x32_bf16(af[mi], bf[ni], acc[mi][ni], 0, 0, 0);

        __syncthreads();
    }

#pragma unroll
    for (int mi = 0; mi < 2; mi++)
#pragma unroll
        for (int ni = 0; ni < 4; ni++) {
            int n = N0 + wn * 64 + ni * 16 + l15;
            float bias_n = bo[n];
            int m0 = M0 + wm * 32 + mi * 16 + quad * 4;
#pragma unroll
            for (int r = 0; r < 4; r++)
                out[(size_t)(m0 + r) * 1024 + n] = acc[mi][ni][r] + bias_n;
        }
}

// ---------------- flash attention (unchanged from round 7) ----------------
__global__ __launch_bounds__(256, 2) void attn_kernel(
    const u16* __restrict__ qe, const u16* __restrict__ ke, const u16* __restrict__ vT,
    u16* __restrict__ out)
{
    __shared__ __align__(16) u16 smem[24576];   // 48 KB
    u16* const KsA = smem;            // 2 x 8192 u16: K tiles [64 rows][128 u16]
    u16* const VtA = smem + 16384;    // 2 x 4096 u16: V tiles [64 d][64 u16]

    const int tid = threadIdx.x;
    const int lane = tid & 63, w = tid >> 6;
    const int kw = w & 1, qw = w >> 1;
    const int l15 = lane & 15, quad = lane >> 4;
    const int lsw = l15 & 7;
    const int lin = blockIdx.x;                       // 512 blocks
    const int bh = (lin & 7) + ((lin >> 3) & 3) * 8;  // lin%8 == bh%8 -> XCD affinity
    const int q0 = (lin >> 5) * 128;

    const u16* qeb = qe + (size_t)bh * 2048 * 96;
    const u16* keb = ke + (size_t)bh * 2048 * 96;
    const u16* vTb = vT + (size_t)bh * 64 * 2048;

    // --- pre-swizzled staging source offsets; wave w owns tile rows [16w,16w+16) ---
    size_t koff[4];
#pragma unroll
    for (int j = 0; j < 4; j++) {
        int r = w * 16 + j * 4 + (lane >> 4);
        int c = (lane & 15) ^ (r & 7);
        if (c >= 12) c -= 8;   // OOB clamp: position never read; keep fetch in-row
        koff[j] = (size_t)r * 96 + (size_t)(c * 8);
    }
    size_t voff[2];
#pragma unroll
    for (int j = 0; j < 2; j++) {
        int r = w * 16 + j * 8 + (lane >> 3);
        voff[j] = (size_t)r * 2048 + (size_t)((((lane & 7) ^ (r & 7)) * 8));
    }

    // prologue: stage tile 0 into buf 0 (flies under the Q-fragment loads below)
#pragma unroll
    for (int j = 0; j < 4; j++) async_cp16(keb + koff[j], KsA + w * 2048 + j * 512);
#pragma unroll
    for (int j = 0; j < 2; j++) async_cp16(vTb + voff[j], VtA + w * 1024 + j * 512);

    bf16x8 bq[4][3];
#pragma unroll
    for (int s = 0; s < 4; s++) {
        const u16* qrow = qeb + (size_t)(q0 + qw * 64 + s * 16 + l15) * 96;
#pragma unroll
        for (int ks = 0; ks < 3; ks++) bq[s][ks] = *(const bf16x8*)(qrow + ks * 32 + quad * 8);
    }

    f32x4 O[4][4];
    float l_part[4];
#pragma unroll
    for (int s = 0; s < 4; s++) {
        l_part[s] = 0.f;
#pragma unroll
        for (int dt = 0; dt < 4; dt++) O[s][dt] = (f32x4){0.f, 0.f, 0.f, 0.f};
    }

    __syncthreads();   // tile 0 resident (vmcnt drained by barrier)

    for (int kb = 0; kb < 2048; kb += 64) {
        const int buf = (kb >> 6) & 1;
        const u16* Ks = KsA + buf * 8192;
        const u16* Vt = VtA + buf * 4096;

        if (kb + 64 < 2048) {   // prefetch next tile into idle buffer (async, drained at barrier)
            u16* Ksn = KsA + (buf ^ 1) * 8192;
            u16* Vtn = VtA + (buf ^ 1) * 4096;
            const size_t kb96 = (size_t)(kb + 64) * 96;
#pragma unroll
            for (int j = 0; j < 4; j++) async_cp16(keb + kb96 + koff[j], Ksn + w * 2048 + j * 512);
#pragma unroll
            for (int j = 0; j < 2; j++) async_cp16(vTb + (size_t)(kb + 64) + voff[j], Vtn + w * 1024 + j * 512);
        }

        f32x4 S[4][2];
#pragma unroll
        for (int s = 0; s < 4; s++)
#pragma unroll
            for (int nt = 0; nt < 2; nt++) S[s][nt] = (f32x4){0.f, 0.f, 0.f, 0.f};

        __builtin_amdgcn_s_setprio(1);
#pragma unroll
        for (int ks = 0; ks < 3; ks++) {
            bf16x8 ak[2];
#pragma unroll
            for (int nt = 0; nt < 2; nt++)
                ak[nt] = *(const bf16x8*)(Ks + (kw * 32 + nt * 16 + l15) * 128 + (((ks * 4 + quad) ^ lsw) & 15) * 8);
#pragma unroll
            for (int s = 0; s < 4; s++)
#pragma unroll
                for (int nt = 0; nt < 2; nt++)
                    S[s][nt] = __builtin_amdgcn_mfma_f32_16x16x32_bf16(ak[nt], bq[s][ks], S[s][nt], 0, 0, 0);
        }
        __builtin_amdgcn_s_setprio(0);

        // V fragments for PV
        bf16x8 av[4];
#pragma unroll
        for (int dt = 0; dt < 4; dt++)
            av[dt] = *(const bf16x8*)(Vt + (dt * 16 + l15) * 64 + (((kw * 4 + quad) ^ lsw) & 7) * 8);

        // per-s: exp + pack + in-register redistribution -> 4 PV MFMAs
#pragma unroll
        for (int s = 0; s < 4; s++) {
            float sum = 0.f;
#pragma unroll
            for (int nt = 0; nt < 2; nt++)
#pragma unroll
                for (int r = 0; r < 4; r++) {
                    float p = __builtin_amdgcn_exp2f(S[s][nt][r]);
                    S[s][nt][r] = p;
                    sum += p;
                }
            l_part[s] += sum;
            u32 a0 = cvtpk2(S[s][0][0], S[s][0][1]);   // U[nt=0][p=0]
            u32 b0 = cvtpk2(S[s][1][0], S[s][1][1]);   // U[1][0]
            u32 a1 = cvtpk2(S[s][0][2], S[s][0][3]);   // U[0][1]
            u32 b1 = cvtpk2(S[s][1][2], S[s][1][3]);   // U[1][1]
            permlane32_swap(a0, b0);   // reg-bit nt <-> lane-bit5
            permlane32_swap(a1, b1);
            permlane16_swap(a0, b0);   // reg-bit <-> lane-bit4
            permlane16_swap(a1, b1);
            bf16x8 pv = __builtin_bit_cast(bf16x8, (u32x4){a0, a1, b0, b1});
            __builtin_amdgcn_s_setprio(1);
#pragma unroll
            for (int dt = 0; dt < 4; dt++)
                O[s][dt] = __builtin_amdgcn_mfma_f32_16x16x32_bf16(av[dt], pv, O[s][dt], 0, 0, 0);
            __builtin_amdgcn_s_setprio(0);
        }

        __syncthreads();  // buf read-done + prefetch vmcnt drain
    }

    float* const Ored = (float*)smem;                 // 128 x 68 floats = 34816 B
    float* const Lr = (float*)(smem + 17664);         // byte 35328, 512 B
    if (kw == 1) {
#pragma unroll
        for (int s = 0; s < 4; s++) {
            float l = l_part[s];
            l += __shfl_xor(l, 16);
            l += __shfl_xor(l, 32);
            if (lane < 16) Lr[qw * 64 + s * 16 + l15] = l;
            int qrow = qw * 64 + s * 16 + l15;
#pragma unroll
            for (int dt = 0; dt < 4; dt++) {
                int dc = dt ^ (l15 & 3);
                *(float4*)(Ored + qrow * 68 + dc * 16 + quad * 4) =
                    make_float4(O[s][dt][0], O[s][dt][1], O[s][dt][2], O[s][dt][3]);
            }
        }
    }
    __syncthreads();
    if (kw == 0) {
        const int b = bh >> 4, h = bh & 15;
#pragma unroll
        for (int s = 0; s < 4; s++) {
            float l = l_part[s];
            l += __shfl_xor(l, 16);
            l += __shfl_xor(l, 32);
            int qrow = qw * 64 + s * 16 + l15;
            l += Lr[qrow];
            float linv = 1.0f / l;
            int tq = q0 + qrow;
#pragma unroll
            for (int dt = 0; dt < 4; dt++) {
                int dc = dt ^ (l15 & 3);
                float4 o2 = *(const float4*)(Ored + qrow * 68 + dc * 16 + quad * 4);
                int d = h * 64 + dt * 16 + quad * 4;
                *(uint2*)(out + (size_t)(b * 2048 + tq) * 1024 + d) =
                    make_uint2(cvtpk2((O[s][dt][0] + o2.x) * linv, (O[s][dt][1] + o2.y) * linv),
                               cvtpk2((O[s][dt][2] + o2.z) * linv, (O[s][dt][3] + o2.w) * linv));
            }
        }
    }
}

// ---------------- launch ----------------
extern "C" void kernel_launch(void* const* d_in, const int* in_sizes, int n_in,
                              void* d_out, int out_size, void* d_ws, size_t ws_size,
                              hipStream_t stream)
{
    (void)in_sizes; (void)n_in; (void)out_size; (void)ws_size;
    const float* x   = (const float*)d_in[0];
    const float* Wq  = (const float*)d_in[1];
    const float* bq  = (const float*)d_in[2];
    const float* Wk  = (const float*)d_in[3];
    const float* bk  = (const float*)d_in[4];
    const float* Wv  = (const float*)d_in[5];
    const float* bv  = (const float*)d_in[6];
    const float* Wo  = (const float*)d_in[7];
    const float* bo  = (const float*)d_in[8];
    const float* Wqs = (const float*)d_in[9];
    const float* bqs = (const float*)d_in[10];
    const float* Wks = (const float*)d_in[11];
    const float* bks = (const float*)d_in[12];
    const float* Wvs = (const float*)d_in[13];
    const float* bvs = (const float*)d_in[14];
    const float* temp = (const float*)d_in[15];

    char* ws = (char*)d_ws;
    u16* xb  = (u16*)(ws);                  // 8 MB
    u16* Wqb = (u16*)(ws + 8388608);        // 2 MB
    u16* Wkb = (u16*)(ws + 10485760);       // 2 MB
    u16* Wvb = (u16*)(ws + 12582912);       // 2 MB
    u16* Wob = (u16*)(ws + 14680064);       // 2 MB
    u16* qeb = (u16*)(ws + 16777216);       // 12 MB [B,H,T,96]
    u16* keb = (u16*)(ws + 29360128);       // 12 MB
    u16* vTb = (u16*)(ws + 41943040);       // 8 MB  [B,H,64,T]
    float4* k3b = (float4*)(ws + 50331648); // 1 MB  [B*H*T]
    float4* v3b = (float4*)(ws + 51380224); // 1 MB
    u16* aob = (u16*)(ws + 52428800);       // 8 MB  [B,T,D]

    cast_all_kernel<<<8192, 256, 0, stream>>>(x, Wq, Wk, Wv, Wo, xb, Wqb, Wkb, Wvb, Wob);
    gemm_qkv_kernel<<<768, 256, 0, stream>>>(
        xb, Wqb, Wkb, Wvb, bq, bk, bv, Wqs, bqs, Wks, bks, Wvs, bvs, temp,
        qeb, keb, vTb, k3b, v3b);
    finish_ext_kernel<<<256, 256, 0, stream>>>(k3b, v3b, keb);
    attn_kernel<<<512, 256, 0, stream>>>(qeb, keb, vTb, aob);
    gemm_out_kernel<<<512, 256, 0, stream>>>(aob, Wob, bo, (float*)d_out);
}

// Round 9
// 208.634 us; speedup vs baseline: 1.0455x; 1.0113x over previous
//
#include <hip/hip_runtime.h>
#include <stdint.h>

typedef unsigned short u16;
typedef unsigned int u32;
typedef __attribute__((ext_vector_type(8))) short bf16x8;
typedef __attribute__((ext_vector_type(4))) float f32x4;
typedef __attribute__((ext_vector_type(4))) unsigned int u32x4;

__device__ __forceinline__ u16 f2b(float f) {
    union { float f; u32 u; } t; t.f = f;
    return (u16)((t.u + 0x7FFFu + ((t.u >> 16) & 1u)) >> 16);
}
__device__ __forceinline__ u32 pack2(float a, float b) {
    return (u32)f2b(a) | ((u32)f2b(b) << 16);
}
// single-instruction packed f32->bf16 (RNE)
__device__ __forceinline__ u32 cvtpk2(float lo, float hi) {
    u32 r;
    asm("v_cvt_pk_bf16_f32 %0, %1, %2" : "=v"(r) : "v"(lo), "v"(hi));
    return r;
}
// in-register lane-bit <-> reg-bit exchanges (gfx950)
__device__ __forceinline__ void permlane32_swap(u32& a, u32& b) {
    asm("v_permlane32_swap_b32 %0, %1" : "+v"(a), "+v"(b));
}
__device__ __forceinline__ void permlane16_swap(u32& a, u32& b) {
    asm("v_permlane16_swap_b32 %0, %1" : "+v"(a), "+v"(b));
}

// async global->LDS 16B copy: per-lane global addr, wave-uniform LDS base + lane*16
__device__ __forceinline__ void async_cp16(const u16* g, const u16* lds_base) {
    __builtin_amdgcn_global_load_lds(
        (const __attribute__((address_space(1))) void*)(uintptr_t)g,
        (__attribute__((address_space(3))) void*)(u32)(uintptr_t)lds_base,
        16, 0, 0);
}

// ---------------- fused fp32 -> bf16 cast (x + 4 weights, one launch) ----------------
__global__ void cast_all_kernel(const float* __restrict__ x,
                                const float* __restrict__ Wq, const float* __restrict__ Wk,
                                const float* __restrict__ Wv, const float* __restrict__ Wo,
                                u16* __restrict__ xb, u16* __restrict__ Wqb, u16* __restrict__ Wkb,
                                u16* __restrict__ Wvb, u16* __restrict__ Wob) {
    int i = blockIdx.x * blockDim.x + threadIdx.x;  // float4 index, total 2097152
    const float* s; u16* d; int off;
    if (i < 1048576) { s = x; d = xb; off = i; }
    else {
        int j = i - 1048576;
        int w = j >> 18; off = j & 262143;
        if (w == 0) { s = Wq; d = Wqb; }
        else if (w == 1) { s = Wk; d = Wkb; }
        else if (w == 2) { s = Wv; d = Wvb; }
        else { s = Wo; d = Wob; }
    }
    float4 f = ((const float4*)s)[off];
    ((uint2*)d)[off] = make_uint2(pack2(f.x, f.y), pack2(f.z, f.w));
}

// ---------------- fused QKV GEMM + STP projections + qe/ke/vT emission ----------------
// 128x128 tile (BK=32), XCD decode Mt=lin&31 (round-8, proven).
__global__ __launch_bounds__(256) void gemm_qkv_kernel(
    const u16* __restrict__ xb,
    const u16* __restrict__ Wq, const u16* __restrict__ Wk, const u16* __restrict__ Wv,
    const float* __restrict__ bq, const float* __restrict__ bk, const float* __restrict__ bv,
    const float* __restrict__ Wqs, const float* __restrict__ bqs,
    const float* __restrict__ Wks, const float* __restrict__ bks,
    const float* __restrict__ Wvs, const float* __restrict__ bvs,
    const float* __restrict__ temp_p,
    u16* __restrict__ qe, u16* __restrict__ ke, u16* __restrict__ vT,
    float4* __restrict__ k3b, float4* __restrict__ v3b)
{
    __shared__ __align__(16) u16 As[2 * 128 * 32];   // 16 KB, buf stride 4096 u16
    __shared__ __align__(16) u16 Bs[2 * 128 * 32];   // 16 KB
    const int tid = threadIdx.x;
    const int lane = tid & 63, w = tid >> 6;
    const int wm = w >> 1, wn = w & 1;
    const int l15 = lane & 15, quad = lane >> 4;
    const int lin = blockIdx.x;                 // 768 blocks
    const int M0 = (lin & 31) * 128;            // Mt -> XCD key (lin%8 = Mt%8)
    const int N0 = ((lin >> 5) & 7) * 128;
    const int bz = lin >> 8;                    // 0,1,2

    const u16* W = (bz == 0) ? Wq : (bz == 1) ? Wk : Wv;
    const float* bias = (bz == 0) ? bq : (bz == 1) ? bk : bv;
    const float* Wst = (bz == 0) ? Wqs : (bz == 1) ? Wks : Wvs;
    const float* bst = (bz == 0) ? bqs : (bz == 1) ? bks : bvs;

    f32x4 acc[4][4];
#pragma unroll
    for (int i = 0; i < 4; i++)
#pragma unroll
        for (int j = 0; j < 4; j++) acc[i][j] = (f32x4){0.f, 0.f, 0.f, 0.f};

    const int ca2 = ((lane & 3) ^ ((lane >> 2) & 3)) * 8;
    const u16* Ag = xb + (size_t)(M0 + w * 32 + (lane >> 2)) * 1024 + ca2;
    const u16* Bg = W + (size_t)(N0 + w * 32 + (lane >> 2)) * 1024 + ca2;
    const int dst0 = w * 1024;            // u16 units within a buf
    const int dst1 = w * 1024 + 512;

    // preheader: tile 0 -> buf 0
    async_cp16(Ag, As + dst0);
    async_cp16(Ag + 16 * 1024, As + dst1);
    async_cp16(Bg, Bs + dst0);
    async_cp16(Bg + 16 * 1024, Bs + dst1);
    __syncthreads();   // vmcnt drain: tile 0 resident

    for (int k0 = 0; k0 < 1024; k0 += 32) {
        const int buf = (k0 >> 5) & 1;
        const u16* Asr = As + buf * 4096;
        const u16* Bsr = Bs + buf * 4096;
        if (k0 + 32 < 1024) {   // issue next tile into idle buffer; flies under compute
            const int nb_ = (buf ^ 1) * 4096;
            async_cp16(Ag + k0 + 32, As + nb_ + dst0);
            async_cp16(Ag + 16 * 1024 + k0 + 32, As + nb_ + dst1);
            async_cp16(Bg + k0 + 32, Bs + nb_ + dst0);
            async_cp16(Bg + 16 * 1024 + k0 + 32, Bs + nb_ + dst1);
        }

        bf16x8 af[4], bf[4];
#pragma unroll
        for (int mi = 0; mi < 4; mi++)
            af[mi] = *(const bf16x8*)(Asr + (wm * 64 + mi * 16 + l15) * 32 + ((quad ^ (l15 & 3)) * 8));
#pragma unroll
        for (int ni = 0; ni < 4; ni++)
            bf[ni] = *(const bf16x8*)(Bsr + (wn * 64 + ni * 16 + l15) * 32 + ((quad ^ (l15 & 3)) * 8));
#pragma unroll
        for (int mi = 0; mi < 4; mi++)
#pragma unroll
            for (int ni = 0; ni < 4; ni++)
                acc[mi][ni] = __builtin_amdgcn_mfma_f32_16x16x32_bf16(af[mi], bf[ni], acc[mi][ni], 0, 0, 0);

        __syncthreads();  // single barrier: buf read-done + next tile vmcnt drain
    }

    // ---- epilogue ----
    const float tau = temp_p[0] * 1.44269504088896f;
    const int nb = N0 + wn * 64;
    const int h = nb >> 6;
    float bias_v[4], wst_v[3][4];
#pragma unroll
    for (int ni = 0; ni < 4; ni++) {
        bias_v[ni] = bias[nb + ni * 16 + l15];
#pragma unroll
        for (int c = 0; c < 3; c++) wst_v[c][ni] = Wst[c * 64 + ni * 16 + l15];
    }
    const float bst0 = bst[0], bst1 = bst[1], bst2 = bst[2];

#pragma unroll
    for (int mi = 0; mi < 4; mi++) {
        int m0 = M0 + wm * 64 + mi * 16 + quad * 4;
        int b = m0 >> 11, t0 = m0 & 2047;
        float p0[4], p1[4], p2[4];
#pragma unroll
        for (int r = 0; r < 4; r++) {
            float a0 = 0.f, a1 = 0.f, a2 = 0.f;
#pragma unroll
            for (int ni = 0; ni < 4; ni++) {
                float v = acc[mi][ni][r] + bias_v[ni];
                a0 += v * wst_v[0][ni];
                a1 += v * wst_v[1][ni];
                a2 += v * wst_v[2][ni];
            }
#pragma unroll
            for (int off = 1; off < 16; off <<= 1) {
                a0 += __shfl_xor(a0, off);
                a1 += __shfl_xor(a1, off);
                a2 += __shfl_xor(a2, off);
            }
            p0[r] = a0 + bst0; p1[r] = a1 + bst1; p2[r] = a2 + bst2;
        }

        if (bz == 0) {
#pragma unroll
            for (int r = 0; r < 4; r++) {
                size_t row = (size_t)((b * 16 + h) * 2048 + (t0 + r));
                u16* qer = qe + row * 96;
#pragma unroll
                for (int ni = 0; ni < 4; ni++)
                    qer[ni * 16 + l15] = f2b((acc[mi][ni][r] + bias_v[ni]) * tau);
                if (l15 == 0) {
                    *(u32*)(qer + 64) = pack2(p0[r] * tau, p1[r] * tau);
                    *(u32*)(qer + 66) = (u32)f2b(p2[r] * tau);
                    uint2 z = make_uint2(0u, 0u);
#pragma unroll
                    for (int j = 68; j < 96; j += 4) *(uint2*)(qer + j) = z;
                }
            }
        } else if (bz == 1) {
#pragma unroll
            for (int r = 0; r < 4; r++) {
                size_t row = (size_t)((b * 16 + h) * 2048 + (t0 + r));
                u16* ker = ke + row * 96;
#pragma unroll
                for (int ni = 0; ni < 4; ni++)
                    ker[ni * 16 + l15] = f2b(acc[mi][ni][r] + bias_v[ni]);
                if (l15 == 0)
                    k3b[row] = make_float4(p0[r], p1[r], p2[r], 0.f);
            }
        } else {
#pragma unroll
            for (int ni = 0; ni < 4; ni++) {
                int hd = ni * 16 + l15;
                float v0 = acc[mi][ni][0] + bias_v[ni];
                float v1 = acc[mi][ni][1] + bias_v[ni];
                float v2 = acc[mi][ni][2] + bias_v[ni];
                float v3 = acc[mi][ni][3] + bias_v[ni];
                *(uint2*)(vT + ((size_t)((b * 16 + h) * 64 + hd)) * 2048 + t0) =
                    make_uint2(pack2(v0, v1), pack2(v2, v3));
            }
            if (l15 == 0) {
#pragma unroll
                for (int r = 0; r < 4; r++) {
                    size_t row = (size_t)((b * 16 + h) * 2048 + (t0 + r));
                    v3b[row] = make_float4(p0[r], p1[r], p2[r], 0.f);
                }
            }
        }
    }
}

// ---------------- finish: ke[64:67] = cross(k3,v3), ke[67:96] = 0 ----------------
__global__ void finish_ext_kernel(const float4* __restrict__ k3b, const float4* __restrict__ v3b,
                                  u16* __restrict__ ke)
{
    int row = blockIdx.x * blockDim.x + threadIdx.x;
    if (row >= 2 * 16 * 2048) return;
    float4 k3 = k3b[row];
    float4 v3 = v3b[row];
    float c0 = k3.y * v3.z - k3.z * v3.y;
    float c1 = k3.z * v3.x - k3.x * v3.z;
    float c2 = k3.x * v3.y - k3.y * v3.x;
    u16* ker = ke + (size_t)row * 96;
    *(u32*)(ker + 64) = pack2(c0, c1);
    *(u32*)(ker + 66) = (u32)f2b(c2);
    uint2 z = make_uint2(0u, 0u);
#pragma unroll
    for (int j = 68; j < 96; j += 4) *(uint2*)(ker + j) = z;
}

// ---------------- out-projection GEMM: 64x128 tiles, double-buffered async ----------
// XCD-aware linear decode (same-A blocks -> same XCD), proven in round 5.
__global__ __launch_bounds__(256) void gemm_out_kernel(
    const u16* __restrict__ ao, const u16* __restrict__ Wo, const float* __restrict__ bo,
    float* __restrict__ out)
{
    __shared__ __align__(16) u16 As[2 * 64 * 32];
    __shared__ __align__(16) u16 Bs[2 * 128 * 32];
    const int tid = threadIdx.x;
    const int lane = tid & 63, w = tid >> 6;
    const int wm = w >> 1, wn = w & 1;
    const int l15 = lane & 15, quad = lane >> 4;
    const int lin = blockIdx.x;
    const int M0 = (lin & 63) * 64;
    const int N0 = (lin >> 6) * 128;

    f32x4 acc[2][4];
#pragma unroll
    for (int i = 0; i < 2; i++)
#pragma unroll
        for (int j = 0; j < 4; j++) acc[i][j] = (f32x4){0.f, 0.f, 0.f, 0.f};

    int ra = tid >> 2, ca = ((tid & 3) ^ (ra & 3)) * 8;
    const u16* Aga = ao + (size_t)(M0 + ra) * 1024 + ca;
    const u16* Bg0 = Wo + (size_t)(N0 + ra) * 1024 + ca;
    const u16* Bg1 = Wo + (size_t)(N0 + ra + 64) * 1024 + ca;
    const int aoff = (w * 64) * 8;
    const int boff0 = (w * 64) * 8;
    const int boff1 = (256 + w * 64) * 8;

    async_cp16(Aga, As + aoff);
    async_cp16(Bg0, Bs + boff0);
    async_cp16(Bg1, Bs + boff1);
    __syncthreads();

    for (int k0 = 0; k0 < 1024; k0 += 32) {
        const int buf = (k0 >> 5) & 1;
        const u16* Asr = As + buf * 2048;
        const u16* Bsr = Bs + buf * 4096;
        if (k0 + 32 < 1024) {
            const int nb_ = buf ^ 1;
            async_cp16(Aga + k0 + 32, As + nb_ * 2048 + aoff);
            async_cp16(Bg0 + k0 + 32, Bs + nb_ * 4096 + boff0);
            async_cp16(Bg1 + k0 + 32, Bs + nb_ * 4096 + boff1);
        }

        bf16x8 af[2], bf[4];
#pragma unroll
        for (int mi = 0; mi < 2; mi++)
            af[mi] = *(const bf16x8*)(Asr + (wm * 32 + mi * 16 + l15) * 32 + ((quad ^ (l15 & 3)) * 8));
#pragma unroll
        for (int ni = 0; ni < 4; ni++)
            bf[ni] = *(const bf16x8*)(Bsr + (wn * 64 + ni * 16 + l15) * 32 + ((quad ^ (l15 & 3)) * 8));
#pragma unroll
        for (int mi = 0; mi < 2; mi++)
#pragma unroll
            for (int ni = 0; ni < 4; ni++)
                acc[mi][ni] = __builtin_amdgcn_mfma_f32_16x16x32_bf16(af[mi], bf[ni], acc[mi][ni], 0, 0, 0);

        __syncthreads();
    }

#pragma unroll
    for (int mi = 0; mi < 2; mi++)
#pragma unroll
        for (int ni = 0; ni < 4; ni++) {
            int n = N0 + wn * 64 + ni * 16 + l15;
            float bias_n = bo[n];
            int m0 = M0 + wm * 32 + mi * 16 + quad * 4;
#pragma unroll
            for (int r = 0; r < 4; r++)
                out[(size_t)(m0 + r) * 1024 + n] = acc[mi][ni][r] + bias_n;
        }
}

// ---------------- flash attention ----------------
// Round-18: 512-thread blocks (8 waves). Same 128-row q-tile and identical
// HBM/L2 traffic; waves/CU 8 -> 16 (occupancy was THE binding resource:
// round-7 showed FETCH collapse with zero time change). Per-wave state halves
// (qw in 0..3 handles 32 q-rows: O[2][4], S[2][2], bq[2][3]) -> VGPR ~104->~80.
// Staging remap for 8 waves: wave w owns 8 rows (K: 2 issues, V: 1), same
// chunk = pos^(row&7) involution + OOB clamp.
__global__ __launch_bounds__(512, 2) void attn_kernel(
    const u16* __restrict__ qe, const u16* __restrict__ ke, const u16* __restrict__ vT,
    u16* __restrict__ out)
{
    __shared__ __align__(16) u16 smem[24576];   // 48 KB
    u16* const KsA = smem;            // 2 x 8192 u16: K tiles [64 rows][128 u16]
    u16* const VtA = smem + 16384;    // 2 x 4096 u16: V tiles [64 d][64 u16]

    const int tid = threadIdx.x;
    const int lane = tid & 63, w = tid >> 6;          // 8 waves
    const int kw = w & 1, qw = w >> 1;                // qw in 0..3
    const int l15 = lane & 15, quad = lane >> 4;
    const int lsw = l15 & 7;
    const int lin = blockIdx.x;                       // 512 blocks
    const int bh = (lin & 7) + ((lin >> 3) & 3) * 8;  // lin%8 == bh%8 -> XCD affinity
    const int q0 = (lin >> 5) * 128;

    const u16* qeb = qe + (size_t)bh * 2048 * 96;
    const u16* keb = ke + (size_t)bh * 2048 * 96;
    const u16* vTb = vT + (size_t)bh * 64 * 2048;

    // --- pre-swizzled staging source offsets; wave w owns tile rows [8w, 8w+8) ---
    // K issue j (0,1): LDS dest u16 = w*1024 + j*512 + lane*8
    //   -> row = 8w + 4j + (lane>>4), pos = lane&15, chunk = pos^(row&7), OOB clamp
    u32 koff[2];
#pragma unroll
    for (int j = 0; j < 2; j++) {
        int r = w * 8 + j * 4 + (lane >> 4);
        int c = (lane & 15) ^ (r & 7);
        if (c >= 12) c -= 8;   // position never read; keep fetch in-row
        koff[j] = (u32)(r * 96 + c * 8);
    }
    // V issue: LDS dest u16 = w*512 + lane*8 -> row = 8w + (lane>>3), pos = lane&7
    u32 voff;
    {
        int r = w * 8 + (lane >> 3);
        voff = (u32)(r * 2048 + (((lane & 7) ^ (r & 7)) * 8));
    }

    // prologue: stage tile 0 into buf 0 (flies under the Q-fragment loads below)
#pragma unroll
    for (int j = 0; j < 2; j++) async_cp16(keb + koff[j], KsA + w * 1024 + j * 512);
    async_cp16(vTb + voff, VtA + w * 512);

    bf16x8 bq[2][3];
#pragma unroll
    for (int s = 0; s < 2; s++) {
        const u16* qrow = qeb + (size_t)(q0 + qw * 32 + s * 16 + l15) * 96;
#pragma unroll
        for (int ks = 0; ks < 3; ks++) bq[s][ks] = *(const bf16x8*)(qrow + ks * 32 + quad * 8);
    }

    f32x4 O[2][4];
    float l_part[2];
#pragma unroll
    for (int s = 0; s < 2; s++) {
        l_part[s] = 0.f;
#pragma unroll
        for (int dt = 0; dt < 4; dt++) O[s][dt] = (f32x4){0.f, 0.f, 0.f, 0.f};
    }

    __syncthreads();   // tile 0 resident (vmcnt drained by barrier)

    for (int kb = 0; kb < 2048; kb += 64) {
        const int buf = (kb >> 6) & 1;
        const u16* Ks = KsA + buf * 8192;
        const u16* Vt = VtA + buf * 4096;

        if (kb + 64 < 2048) {   // prefetch next tile into idle buffer (async, drained at barrier)
            u16* Ksn = KsA + (buf ^ 1) * 8192;
            u16* Vtn = VtA + (buf ^ 1) * 4096;
            const size_t kb96 = (size_t)(kb + 64) * 96;
#pragma unroll
            for (int j = 0; j < 2; j++) async_cp16(keb + kb96 + koff[j], Ksn + w * 1024 + j * 512);
            async_cp16(vTb + (size_t)(kb + 64) + voff, Vtn + w * 512);
        }

        f32x4 S[2][2];
#pragma unroll
        for (int s = 0; s < 2; s++)
#pragma unroll
            for (int nt = 0; nt < 2; nt++) S[s][nt] = (f32x4){0.f, 0.f, 0.f, 0.f};

        __builtin_amdgcn_s_setprio(1);
#pragma unroll
        for (int ks = 0; ks < 3; ks++) {
            bf16x8 ak[2];
#pragma unroll
            for (int nt = 0; nt < 2; nt++)
                ak[nt] = *(const bf16x8*)(Ks + (kw * 32 + nt * 16 + l15) * 128 + (((ks * 4 + quad) ^ lsw) & 15) * 8);
#pragma unroll
            for (int s = 0; s < 2; s++)
#pragma unroll
                for (int nt = 0; nt < 2; nt++)
                    S[s][nt] = __builtin_amdgcn_mfma_f32_16x16x32_bf16(ak[nt], bq[s][ks], S[s][nt], 0, 0, 0);
        }
        __builtin_amdgcn_s_setprio(0);

        // V fragments for PV
        bf16x8 av[4];
#pragma unroll
        for (int dt = 0; dt < 4; dt++)
            av[dt] = *(const bf16x8*)(Vt + (dt * 16 + l15) * 64 + (((kw * 4 + quad) ^ lsw) & 7) * 8);

        // per-s: exp + pack + in-register redistribution -> 4 PV MFMAs
#pragma unroll
        for (int s = 0; s < 2; s++) {
            float sum = 0.f;
#pragma unroll
            for (int nt = 0; nt < 2; nt++)
#pragma unroll
                for (int r = 0; r < 4; r++) {
                    float p = __builtin_amdgcn_exp2f(S[s][nt][r]);
                    S[s][nt][r] = p;
                    sum += p;
                }
            l_part[s] += sum;
            u32 a0 = cvtpk2(S[s][0][0], S[s][0][1]);   // U[nt=0][p=0]
            u32 b0 = cvtpk2(S[s][1][0], S[s][1][1]);   // U[1][0]
            u32 a1 = cvtpk2(S[s][0][2], S[s][0][3]);   // U[0][1]
            u32 b1 = cvtpk2(S[s][1][2], S[s][1][3]);   // U[1][1]
            permlane32_swap(a0, b0);   // reg-bit nt <-> lane-bit5
            permlane32_swap(a1, b1);
            permlane16_swap(a0, b0);   // reg-bit <-> lane-bit4
            permlane16_swap(a1, b1);
            bf16x8 pv = __builtin_bit_cast(bf16x8, (u32x4){a0, a1, b0, b1});
            __builtin_amdgcn_s_setprio(1);
#pragma unroll
            for (int dt = 0; dt < 4; dt++)
                O[s][dt] = __builtin_amdgcn_mfma_f32_16x16x32_bf16(av[dt], pv, O[s][dt], 0, 0, 0);
            __builtin_amdgcn_s_setprio(0);
        }

        __syncthreads();  // buf read-done + prefetch vmcnt drain
    }

    float* const Ored = (float*)smem;                 // 128 x 68 floats = 34816 B
    float* const Lr = (float*)(smem + 17664);         // byte 35328, 512 B
    if (kw == 1) {
#pragma unroll
        for (int s = 0; s < 2; s++) {
            float l = l_part[s];
            l += __shfl_xor(l, 16);
            l += __shfl_xor(l, 32);
            int qrow = qw * 32 + s * 16 + l15;
            if (lane < 16) Lr[qrow] = l;
#pragma unroll
            for (int dt = 0; dt < 4; dt++) {
                int dc = dt ^ (l15 & 3);
                *(float4*)(Ored + qrow * 68 + dc * 16 + quad * 4) =
                    make_float4(O[s][dt][0], O[s][dt][1], O[s][dt][2], O[s][dt][3]);
            }
        }
    }
    __syncthreads();
    if (kw == 0) {
        const int b = bh >> 4, h = bh & 15;
#pragma unroll
        for (int s = 0; s < 2; s++) {
            float l = l_part[s];
            l += __shfl_xor(l, 16);
            l += __shfl_xor(l, 32);
            int qrow = qw * 32 + s * 16 + l15;
            l += Lr[qrow];
            float linv = 1.0f / l;
            int tq = q0 + qrow;
#pragma unroll
            for (int dt = 0; dt < 4; dt++) {
                int dc = dt ^ (l15 & 3);
                float4 o2 = *(const float4*)(Ored + qrow * 68 + dc * 16 + quad * 4);
                int d = h * 64 + dt * 16 + quad * 4;
                *(uint2*)(out + (size_t)(b * 2048 + tq) * 1024 + d) =
                    make_uint2(cvtpk2((O[s][dt][0] + o2.x) * linv, (O[s][dt][1] + o2.y) * linv),
                               cvtpk2((O[s][dt][2] + o2.z) * linv, (O[s][dt][3] + o2.w) * linv));
            }
        }
    }
}

// ---------------- launch ----------------
extern "C" void kernel_launch(void* const* d_in, const int* in_sizes, int n_in,
                              void* d_out, int out_size, void* d_ws, size_t ws_size,
                              hipStream_t stream)
{
    (void)in_sizes; (void)n_in; (void)out_size; (void)ws_size;
    const float* x   = (const float*)d_in[0];
    const float* Wq  = (const float*)d_in[1];
    const float* bq  = (const float*)d_in[2];
    const float* Wk  = (const float*)d_in[3];
    const float* bk  = (const float*)d_in[4];
    const float* Wv  = (const float*)d_in[5];
    const float* bv  = (const float*)d_in[6];
    const float* Wo  = (const float*)d_in[7];
    const float* bo  = (const float*)d_in[8];
    const float* Wqs = (const float*)d_in[9];
    const float* bqs = (const float*)d_in[10];
    const float* Wks = (const float*)d_in[11];
    const float* bks = (const float*)d_in[12];
    const float* Wvs = (const float*)d_in[13];
    const float* bvs = (const float*)d_in[14];
    const float* temp = (const float*)d_in[15];

    char* ws = (char*)d_ws;
    u16* xb  = (u16*)(ws);                  // 8 MB
    u16* Wqb = (u16*)(ws + 8388608);        // 2 MB
    u16* Wkb = (u16*)(ws + 10485760);       // 2 MB
    u16* Wvb = (u16*)(ws + 12582912);       // 2 MB
    u16* Wob = (u16*)(ws + 14680064);       // 2 MB
    u16* qeb = (u16*)(ws + 16777216);       // 12 MB [B,H,T,96]
    u16* keb = (u16*)(ws + 29360128);       // 12 MB
    u16* vTb = (u16*)(ws + 41943040);       // 8 MB  [B,H,64,T]
    float4* k3b = (float4*)(ws + 50331648); // 1 MB  [B*H*T]
    float4* v3b = (float4*)(ws + 51380224); // 1 MB
    u16* aob = (u16*)(ws + 52428800);       // 8 MB  [B,T,D]

    cast_all_kernel<<<8192, 256, 0, stream>>>(x, Wq, Wk, Wv, Wo, xb, Wqb, Wkb, Wvb, Wob);
    gemm_qkv_kernel<<<768, 256, 0, stream>>>(
        xb, Wqb, Wkb, Wvb, bq, bk, bv, Wqs, bqs, Wks, bks, Wvs, bvs, temp,
        qeb, keb, vTb, k3b, v3b);
    finish_ext_kernel<<<256, 256, 0, stream>>>(k3b, v3b, keb);
    attn_kernel<<<512, 512, 0, stream>>>(qeb, keb, vTb, aob);
    gemm_out_kernel<<<512, 256, 0, stream>>>(aob, Wob, bo, (float*)d_out);
}

// Round 10
// 205.753 us; speedup vs baseline: 1.0602x; 1.0140x over previous
//
#include <hip/hip_runtime.h>
#include <stdint.h>

typedef unsigned short u16;
typedef unsigned int u32;
typedef __attribute__((ext_vector_type(8))) short bf16x8;
typedef __attribute__((ext_vector_type(4))) float f32x4;
typedef __attribute__((ext_vector_type(4))) unsigned int u32x4;

__device__ __forceinline__ u16 f2b(float f) {
    union { float f; u32 u; } t; t.f = f;
    return (u16)((t.u + 0x7FFFu + ((t.u >> 16) & 1u)) >> 16);
}
__device__ __forceinline__ u32 pack2(float a, float b) {
    return (u32)f2b(a) | ((u32)f2b(b) << 16);
}
// single-instruction packed f32->bf16 (RNE)
__device__ __forceinline__ u32 cvtpk2(float lo, float hi) {
    u32 r;
    asm("v_cvt_pk_bf16_f32 %0, %1, %2" : "=v"(r) : "v"(lo), "v"(hi));
    return r;
}
// in-register lane-bit <-> reg-bit exchanges (gfx950)
__device__ __forceinline__ void permlane32_swap(u32& a, u32& b) {
    asm("v_permlane32_swap_b32 %0, %1" : "+v"(a), "+v"(b));
}
__device__ __forceinline__ void permlane16_swap(u32& a, u32& b) {
    asm("v_permlane16_swap_b32 %0, %1" : "+v"(a), "+v"(b));
}

// async global->LDS 16B copy: per-lane global addr, wave-uniform LDS base + lane*16
__device__ __forceinline__ void async_cp16(const u16* g, const u16* lds_base) {
    __builtin_amdgcn_global_load_lds(
        (const __attribute__((address_space(1))) void*)(uintptr_t)g,
        (__attribute__((address_space(3))) void*)(u32)(uintptr_t)lds_base,
        16, 0, 0);
}

// ---------------- fused fp32 -> bf16 cast (x + 4 weights, one launch) ----------------
__global__ void cast_all_kernel(const float* __restrict__ x,
                                const float* __restrict__ Wq, const float* __restrict__ Wk,
                                const float* __restrict__ Wv, const float* __restrict__ Wo,
                                u16* __restrict__ xb, u16* __restrict__ Wqb, u16* __restrict__ Wkb,
                                u16* __restrict__ Wvb, u16* __restrict__ Wob) {
    int i = blockIdx.x * blockDim.x + threadIdx.x;  // float4 index, total 2097152
    const float* s; u16* d; int off;
    if (i < 1048576) { s = x; d = xb; off = i; }
    else {
        int j = i - 1048576;
        int w = j >> 18; off = j & 262143;
        if (w == 0) { s = Wq; d = Wqb; }
        else if (w == 1) { s = Wk; d = Wkb; }
        else if (w == 2) { s = Wv; d = Wvb; }
        else { s = Wo; d = Wob; }
    }
    float4 f = ((const float4*)s)[off];
    ((uint2*)d)[off] = make_uint2(pack2(f.x, f.y), pack2(f.z, f.w));
}

// ---------------- fused QKV GEMM + STP projections + qe/ke/vT emission ----------------
// Round-19: 64x128 tile (measured faster than 128^2: 53.6 vs 58.4 us, R7 vs R9)
// with BK=64 -> 16 iterations instead of 32, HALVING the per-iter vmcnt(0)+barrier
// drains that dominate (MfmaUtil pinned at 17% regardless of tile). LDS 48 KB
// (A 2x8KB + B 2x16KB) keeps 3 blocks/CU (m132's BK=128 failure was the 64KB ->
// 2 blocks/CU occupancy cliff; avoided here). Staging: 64-u16 rows = 8 chunks,
// chunk = pos^(row&7) involution (no OOB case); fragment read at position
// (kk*4+quad)^(row&7); the XOR also breaks the 128-B row-stride bank alignment.
// XCD decode M0=(lin&63)*64 (same-A blocks -> same XCD, proven round 5).
__global__ __launch_bounds__(256) void gemm_qkv_kernel(
    const u16* __restrict__ xb,
    const u16* __restrict__ Wq, const u16* __restrict__ Wk, const u16* __restrict__ Wv,
    const float* __restrict__ bq, const float* __restrict__ bk, const float* __restrict__ bv,
    const float* __restrict__ Wqs, const float* __restrict__ bqs,
    const float* __restrict__ Wks, const float* __restrict__ bks,
    const float* __restrict__ Wvs, const float* __restrict__ bvs,
    const float* __restrict__ temp_p,
    u16* __restrict__ qe, u16* __restrict__ ke, u16* __restrict__ vT,
    float4* __restrict__ k3b, float4* __restrict__ v3b)
{
    __shared__ __align__(16) u16 As[2 * 64 * 64];    // 16 KB, buf stride 4096 u16
    __shared__ __align__(16) u16 Bs[2 * 128 * 64];   // 32 KB, buf stride 8192 u16
    const int tid = threadIdx.x;
    const int lane = tid & 63, w = tid >> 6;
    const int wm = w >> 1, wn = w & 1;
    const int l15 = lane & 15, quad = lane >> 4;
    const int lin = blockIdx.x;                 // 1536 blocks
    const int M0 = (lin & 63) * 64;             // Mt -> XCD key (lin%8 = Mt%8)
    const int N0 = ((lin >> 6) & 7) * 128;
    const int bz = lin >> 9;                    // 0,1,2

    const u16* W = (bz == 0) ? Wq : (bz == 1) ? Wk : Wv;
    const float* bias = (bz == 0) ? bq : (bz == 1) ? bk : bv;
    const float* Wst = (bz == 0) ? Wqs : (bz == 1) ? Wks : Wvs;
    const float* bst = (bz == 0) ? bqs : (bz == 1) ? bks : bvs;

    f32x4 acc[2][4];
#pragma unroll
    for (int i = 0; i < 2; i++)
#pragma unroll
        for (int j = 0; j < 4; j++) acc[i][j] = (f32x4){0.f, 0.f, 0.f, 0.f};

    // --- pre-swizzled staging source offsets (BK=64: 8 chunks of 8 u16 per row) ---
    const int lr3 = lane >> 3, lp = lane & 7;
    u32 aoff[2];                                 // A: wave w owns rows [16w,16w+16)
#pragma unroll
    for (int j = 0; j < 2; j++) {
        int r = w * 16 + j * 8 + lr3;
        aoff[j] = (u32)(r * 1024 + ((lp ^ (r & 7)) * 8));
    }
    u32 boff[4];                                 // B: wave w owns rows [32w,32w+32)
#pragma unroll
    for (int j = 0; j < 4; j++) {
        int r = w * 32 + j * 8 + lr3;
        boff[j] = (u32)(r * 1024 + ((lp ^ (r & 7)) * 8));
    }
    const u16* Ag = xb + (size_t)M0 * 1024;
    const u16* Bg = W + (size_t)N0 * 1024;

    // preheader: tile 0 -> buf 0
#pragma unroll
    for (int j = 0; j < 2; j++) async_cp16(Ag + aoff[j], As + w * 1024 + j * 512);
#pragma unroll
    for (int j = 0; j < 4; j++) async_cp16(Bg + boff[j], Bs + w * 2048 + j * 512);
    __syncthreads();   // vmcnt drain: tile 0 resident

    for (int k0 = 0; k0 < 1024; k0 += 64) {
        const int buf = (k0 >> 6) & 1;
        const u16* Asr = As + buf * 4096;
        const u16* Bsr = Bs + buf * 8192;
        if (k0 + 64 < 1024) {   // issue next tile into idle buffer; flies under compute
            const int nb_ = buf ^ 1;
#pragma unroll
            for (int j = 0; j < 2; j++) async_cp16(Ag + (k0 + 64) + aoff[j], As + nb_ * 4096 + w * 1024 + j * 512);
#pragma unroll
            for (int j = 0; j < 4; j++) async_cp16(Bg + (k0 + 64) + boff[j], Bs + nb_ * 8192 + w * 2048 + j * 512);
        }

#pragma unroll
        for (int kk = 0; kk < 2; kk++) {
            bf16x8 af[2], bf[4];
#pragma unroll
            for (int mi = 0; mi < 2; mi++) {
                int ra = wm * 32 + mi * 16 + l15;
                af[mi] = *(const bf16x8*)(Asr + ra * 64 + (((kk * 4 + quad) ^ (ra & 7)) * 8));
            }
#pragma unroll
            for (int ni = 0; ni < 4; ni++) {
                int rb = wn * 64 + ni * 16 + l15;
                bf[ni] = *(const bf16x8*)(Bsr + rb * 64 + (((kk * 4 + quad) ^ (rb & 7)) * 8));
            }
#pragma unroll
            for (int mi = 0; mi < 2; mi++)
#pragma unroll
                for (int ni = 0; ni < 4; ni++)
                    acc[mi][ni] = __builtin_amdgcn_mfma_f32_16x16x32_bf16(af[mi], bf[ni], acc[mi][ni], 0, 0, 0);
        }

        __syncthreads();  // single barrier: buf read-done + next tile vmcnt drain
    }

    // ---- epilogue ----
    const float tau = temp_p[0] * 1.44269504088896f;
    const int nb = N0 + wn * 64;
    const int h = nb >> 6;
    float bias_v[4], wst_v[3][4];
#pragma unroll
    for (int ni = 0; ni < 4; ni++) {
        bias_v[ni] = bias[nb + ni * 16 + l15];
#pragma unroll
        for (int c = 0; c < 3; c++) wst_v[c][ni] = Wst[c * 64 + ni * 16 + l15];
    }
    const float bst0 = bst[0], bst1 = bst[1], bst2 = bst[2];

#pragma unroll
    for (int mi = 0; mi < 2; mi++) {
        int m0 = M0 + wm * 32 + mi * 16 + quad * 4;
        int b = m0 >> 11, t0 = m0 & 2047;
        float p0[4], p1[4], p2[4];
#pragma unroll
        for (int r = 0; r < 4; r++) {
            float a0 = 0.f, a1 = 0.f, a2 = 0.f;
#pragma unroll
            for (int ni = 0; ni < 4; ni++) {
                float v = acc[mi][ni][r] + bias_v[ni];
                a0 += v * wst_v[0][ni];
                a1 += v * wst_v[1][ni];
                a2 += v * wst_v[2][ni];
            }
#pragma unroll
            for (int off = 1; off < 16; off <<= 1) {
                a0 += __shfl_xor(a0, off);
                a1 += __shfl_xor(a1, off);
                a2 += __shfl_xor(a2, off);
            }
            p0[r] = a0 + bst0; p1[r] = a1 + bst1; p2[r] = a2 + bst2;
        }

        if (bz == 0) {
#pragma unroll
            for (int r = 0; r < 4; r++) {
                size_t row = (size_t)((b * 16 + h) * 2048 + (t0 + r));
                u16* qer = qe + row * 96;
#pragma unroll
                for (int ni = 0; ni < 4; ni++)
                    qer[ni * 16 + l15] = f2b((acc[mi][ni][r] + bias_v[ni]) * tau);
                if (l15 == 0) {
                    *(u32*)(qer + 64) = pack2(p0[r] * tau, p1[r] * tau);
                    *(u32*)(qer + 66) = (u32)f2b(p2[r] * tau);
                    uint2 z = make_uint2(0u, 0u);
#pragma unroll
                    for (int j = 68; j < 96; j += 4) *(uint2*)(qer + j) = z;
                }
            }
        } else if (bz == 1) {
#pragma unroll
            for (int r = 0; r < 4; r++) {
                size_t row = (size_t)((b * 16 + h) * 2048 + (t0 + r));
                u16* ker = ke + row * 96;
#pragma unroll
                for (int ni = 0; ni < 4; ni++)
                    ker[ni * 16 + l15] = f2b(acc[mi][ni][r] + bias_v[ni]);
                if (l15 == 0)
                    k3b[row] = make_float4(p0[r], p1[r], p2[r], 0.f);
            }
        } else {
#pragma unroll
            for (int ni = 0; ni < 4; ni++) {
                int hd = ni * 16 + l15;
                float v0 = acc[mi][ni][0] + bias_v[ni];
                float v1 = acc[mi][ni][1] + bias_v[ni];
                float v2 = acc[mi][ni][2] + bias_v[ni];
                float v3 = acc[mi][ni][3] + bias_v[ni];
                *(uint2*)(vT + ((size_t)((b * 16 + h) * 64 + hd)) * 2048 + t0) =
                    make_uint2(pack2(v0, v1), pack2(v2, v3));
            }
            if (l15 == 0) {
#pragma unroll
                for (int r = 0; r < 4; r++) {
                    size_t row = (size_t)((b * 16 + h) * 2048 + (t0 + r));
                    v3b[row] = make_float4(p0[r], p1[r], p2[r], 0.f);
                }
            }
        }
    }
}

// ---------------- finish: ke[64:67] = cross(k3,v3), ke[67:96] = 0 ----------------
__global__ void finish_ext_kernel(const float4* __restrict__ k3b, const float4* __restrict__ v3b,
                                  u16* __restrict__ ke)
{
    int row = blockIdx.x * blockDim.x + threadIdx.x;
    if (row >= 2 * 16 * 2048) return;
    float4 k3 = k3b[row];
    float4 v3 = v3b[row];
    float c0 = k3.y * v3.z - k3.z * v3.y;
    float c1 = k3.z * v3.x - k3.x * v3.z;
    float c2 = k3.x * v3.y - k3.y * v3.x;
    u16* ker = ke + (size_t)row * 96;
    *(u32*)(ker + 64) = pack2(c0, c1);
    *(u32*)(ker + 66) = (u32)f2b(c2);
    uint2 z = make_uint2(0u, 0u);
#pragma unroll
    for (int j = 68; j < 96; j += 4) *(uint2*)(ker + j) = z;
}

// ---------------- out-projection GEMM: 64x128 tile, BK=64 (16 drains) ------------
// Same BK=64 structure as gemm_qkv; grid 512 (2 blocks/CU grid-limited, LDS cap 3
// so zero occupancy cost). XCD decode proven round 5.
__global__ __launch_bounds__(256) void gemm_out_kernel(
    const u16* __restrict__ ao, const u16* __restrict__ Wo, const float* __restrict__ bo,
    float* __restrict__ out)
{
    __shared__ __align__(16) u16 As[2 * 64 * 64];    // 16 KB
    __shared__ __align__(16) u16 Bs[2 * 128 * 64];   // 32 KB
    const int tid = threadIdx.x;
    const int lane = tid & 63, w = tid >> 6;
    const int wm = w >> 1, wn = w & 1;
    const int l15 = lane & 15, quad = lane >> 4;
    const int lin = blockIdx.x;
    const int M0 = (lin & 63) * 64;
    const int N0 = (lin >> 6) * 128;

    f32x4 acc[2][4];
#pragma unroll
    for (int i = 0; i < 2; i++)
#pragma unroll
        for (int j = 0; j < 4; j++) acc[i][j] = (f32x4){0.f, 0.f, 0.f, 0.f};

    const int lr3 = lane >> 3, lp = lane & 7;
    u32 aoff[2];
#pragma unroll
    for (int j = 0; j < 2; j++) {
        int r = w * 16 + j * 8 + lr3;
        aoff[j] = (u32)(r * 1024 + ((lp ^ (r & 7)) * 8));
    }
    u32 boff[4];
#pragma unroll
    for (int j = 0; j < 4; j++) {
        int r = w * 32 + j * 8 + lr3;
        boff[j] = (u32)(r * 1024 + ((lp ^ (r & 7)) * 8));
    }
    const u16* Ag = ao + (size_t)M0 * 1024;
    const u16* Bg = Wo + (size_t)N0 * 1024;

#pragma unroll
    for (int j = 0; j < 2; j++) async_cp16(Ag + aoff[j], As + w * 1024 + j * 512);
#pragma unroll
    for (int j = 0; j < 4; j++) async_cp16(Bg + boff[j], Bs + w * 2048 + j * 512);
    __syncthreads();

    for (int k0 = 0; k0 < 1024; k0 += 64) {
        const int buf = (k0 >> 6) & 1;
        const u16* Asr = As + buf * 4096;
        const u16* Bsr = Bs + buf * 8192;
        if (k0 + 64 < 1024) {
            const int nb_ = buf ^ 1;
#pragma unroll
            for (int j = 0; j < 2; j++) async_cp16(Ag + (k0 + 64) + aoff[j], As + nb_ * 4096 + w * 1024 + j * 512);
#pragma unroll
            for (int j = 0; j < 4; j++) async_cp16(Bg + (k0 + 64) + boff[j], Bs + nb_ * 8192 + w * 2048 + j * 512);
        }

#pragma unroll
        for (int kk = 0; kk < 2; kk++) {
            bf16x8 af[2], bf[4];
#pragma unroll
            for (int mi = 0; mi < 2; mi++) {
                int ra = wm * 32 + mi * 16 + l15;
                af[mi] = *(const bf16x8*)(Asr + ra * 64 + (((kk * 4 + quad) ^ (ra & 7)) * 8));
            }
#pragma unroll
            for (int ni = 0; ni < 4; ni++) {
                int rb = wn * 64 + ni * 16 + l15;
                bf[ni] = *(const bf16x8*)(Bsr + rb * 64 + (((kk * 4 + quad) ^ (rb & 7)) * 8));
            }
#pragma unroll
            for (int mi = 0; mi < 2; mi++)
#pragma unroll
                for (int ni = 0; ni < 4; ni++)
                    acc[mi][ni] = __builtin_amdgcn_mfma_f32_16x16x32_bf16(af[mi], bf[ni], acc[mi][ni], 0, 0, 0);
        }

        __syncthreads();
    }

#pragma unroll
    for (int mi = 0; mi < 2; mi++)
#pragma unroll
        for (int ni = 0; ni < 4; ni++) {
            int n = N0 + wn * 64 + ni * 16 + l15;
            float bias_n = bo[n];
            int m0 = M0 + wm * 32 + mi * 16 + quad * 4;
#pragma unroll
            for (int r = 0; r < 4; r++)
                out[(size_t)(m0 + r) * 1024 + n] = acc[mi][ni][r] + bias_n;
        }
}

// ---------------- flash attention (unchanged from round 9) ----------------
__global__ __launch_bounds__(512, 2) void attn_kernel(
    const u16* __restrict__ qe, const u16* __restrict__ ke, const u16* __restrict__ vT,
    u16* __restrict__ out)
{
    __shared__ __align__(16) u16 smem[24576];   // 48 KB
    u16* const KsA = smem;            // 2 x 8192 u16: K tiles [64 rows][128 u16]
    u16* const VtA = smem + 16384;    // 2 x 4096 u16: V tiles [64 d][64 u16]

    const int tid = threadIdx.x;
    const int lane = tid & 63, w = tid >> 6;          // 8 waves
    const int kw = w & 1, qw = w >> 1;                // qw in 0..3
    const int l15 = lane & 15, quad = lane >> 4;
    const int lsw = l15 & 7;
    const int lin = blockIdx.x;                       // 512 blocks
    const int bh = (lin & 7) + ((lin >> 3) & 3) * 8;  // lin%8 == bh%8 -> XCD affinity
    const int q0 = (lin >> 5) * 128;

    const u16* qeb = qe + (size_t)bh * 2048 * 96;
    const u16* keb = ke + (size_t)bh * 2048 * 96;
    const u16* vTb = vT + (size_t)bh * 64 * 2048;

    // --- pre-swizzled staging source offsets; wave w owns tile rows [8w, 8w+8) ---
    u32 koff[2];
#pragma unroll
    for (int j = 0; j < 2; j++) {
        int r = w * 8 + j * 4 + (lane >> 4);
        int c = (lane & 15) ^ (r & 7);
        if (c >= 12) c -= 8;   // position never read; keep fetch in-row
        koff[j] = (u32)(r * 96 + c * 8);
    }
    u32 voff;
    {
        int r = w * 8 + (lane >> 3);
        voff = (u32)(r * 2048 + (((lane & 7) ^ (r & 7)) * 8));
    }

    // prologue: stage tile 0 into buf 0 (flies under the Q-fragment loads below)
#pragma unroll
    for (int j = 0; j < 2; j++) async_cp16(keb + koff[j], KsA + w * 1024 + j * 512);
    async_cp16(vTb + voff, VtA + w * 512);

    bf16x8 bq[2][3];
#pragma unroll
    for (int s = 0; s < 2; s++) {
        const u16* qrow = qeb + (size_t)(q0 + qw * 32 + s * 16 + l15) * 96;
#pragma unroll
        for (int ks = 0; ks < 3; ks++) bq[s][ks] = *(const bf16x8*)(qrow + ks * 32 + quad * 8);
    }

    f32x4 O[2][4];
    float l_part[2];
#pragma unroll
    for (int s = 0; s < 2; s++) {
        l_part[s] = 0.f;
#pragma unroll
        for (int dt = 0; dt < 4; dt++) O[s][dt] = (f32x4){0.f, 0.f, 0.f, 0.f};
    }

    __syncthreads();   // tile 0 resident (vmcnt drained by barrier)

    for (int kb = 0; kb < 2048; kb += 64) {
        const int buf = (kb >> 6) & 1;
        const u16* Ks = KsA + buf * 8192;
        const u16* Vt = VtA + buf * 4096;

        if (kb + 64 < 2048) {   // prefetch next tile into idle buffer (async, drained at barrier)
            u16* Ksn = KsA + (buf ^ 1) * 8192;
            u16* Vtn = VtA + (buf ^ 1) * 4096;
            const size_t kb96 = (size_t)(kb + 64) * 96;
#pragma unroll
            for (int j = 0; j < 2; j++) async_cp16(keb + kb96 + koff[j], Ksn + w * 1024 + j * 512);
            async_cp16(vTb + (size_t)(kb + 64) + voff, Vtn + w * 512);
        }

        f32x4 S[2][2];
#pragma unroll
        for (int s = 0; s < 2; s++)
#pragma unroll
            for (int nt = 0; nt < 2; nt++) S[s][nt] = (f32x4){0.f, 0.f, 0.f, 0.f};

        __builtin_amdgcn_s_setprio(1);
#pragma unroll
        for (int ks = 0; ks < 3; ks++) {
            bf16x8 ak[2];
#pragma unroll
            for (int nt = 0; nt < 2; nt++)
                ak[nt] = *(const bf16x8*)(Ks + (kw * 32 + nt * 16 + l15) * 128 + (((ks * 4 + quad) ^ lsw) & 15) * 8);
#pragma unroll
            for (int s = 0; s < 2; s++)
#pragma unroll
                for (int nt = 0; nt < 2; nt++)
                    S[s][nt] = __builtin_amdgcn_mfma_f32_16x16x32_bf16(ak[nt], bq[s][ks], S[s][nt], 0, 0, 0);
        }
        __builtin_amdgcn_s_setprio(0);

        // V fragments for PV
        bf16x8 av[4];
#pragma unroll
        for (int dt = 0; dt < 4; dt++)
            av[dt] = *(const bf16x8*)(Vt + (dt * 16 + l15) * 64 + (((kw * 4 + quad) ^ lsw) & 7) * 8);

        // per-s: exp + pack + in-register redistribution -> 4 PV MFMAs
#pragma unroll
        for (int s = 0; s < 2; s++) {
            float sum = 0.f;
#pragma unroll
            for (int nt = 0; nt < 2; nt++)
#pragma unroll
                for (int r = 0; r < 4; r++) {
                    float p = __builtin_amdgcn_exp2f(S[s][nt][r]);
                    S[s][nt][r] = p;
                    sum += p;
                }
            l_part[s] += sum;
            u32 a0 = cvtpk2(S[s][0][0], S[s][0][1]);   // U[nt=0][p=0]
            u32 b0 = cvtpk2(S[s][1][0], S[s][1][1]);   // U[1][0]
            u32 a1 = cvtpk2(S[s][0][2], S[s][0][3]);   // U[0][1]
            u32 b1 = cvtpk2(S[s][1][2], S[s][1][3]);   // U[1][1]
            permlane32_swap(a0, b0);   // reg-bit nt <-> lane-bit5
            permlane32_swap(a1, b1);
            permlane16_swap(a0, b0);   // reg-bit <-> lane-bit4
            permlane16_swap(a1, b1);
            bf16x8 pv = __builtin_bit_cast(bf16x8, (u32x4){a0, a1, b0, b1});
            __builtin_amdgcn_s_setprio(1);
#pragma unroll
            for (int dt = 0; dt < 4; dt++)
                O[s][dt] = __builtin_amdgcn_mfma_f32_16x16x32_bf16(av[dt], pv, O[s][dt], 0, 0, 0);
            __builtin_amdgcn_s_setprio(0);
        }

        __syncthreads();  // buf read-done + prefetch vmcnt drain
    }

    float* const Ored = (float*)smem;                 // 128 x 68 floats = 34816 B
    float* const Lr = (float*)(smem + 17664);         // byte 35328, 512 B
    if (kw == 1) {
#pragma unroll
        for (int s = 0; s < 2; s++) {
            float l = l_part[s];
            l += __shfl_xor(l, 16);
            l += __shfl_xor(l, 32);
            int qrow = qw * 32 + s * 16 + l15;
            if (lane < 16) Lr[qrow] = l;
#pragma unroll
            for (int dt = 0; dt < 4; dt++) {
                int dc = dt ^ (l15 & 3);
                *(float4*)(Ored + qrow * 68 + dc * 16 + quad * 4) =
                    make_float4(O[s][dt][0], O[s][dt][1], O[s][dt][2], O[s][dt][3]);
            }
        }
    }
    __syncthreads();
    if (kw == 0) {
        const int b = bh >> 4, h = bh & 15;
#pragma unroll
        for (int s = 0; s < 2; s++) {
            float l = l_part[s];
            l += __shfl_xor(l, 16);
            l += __shfl_xor(l, 32);
            int qrow = qw * 32 + s * 16 + l15;
            l += Lr[qrow];
            float linv = 1.0f / l;
            int tq = q0 + qrow;
#pragma unroll
            for (int dt = 0; dt < 4; dt++) {
                int dc = dt ^ (l15 & 3);
                float4 o2 = *(const float4*)(Ored + qrow * 68 + dc * 16 + quad * 4);
                int d = h * 64 + dt * 16 + quad * 4;
                *(uint2*)(out + (size_t)(b * 2048 + tq) * 1024 + d) =
                    make_uint2(cvtpk2((O[s][dt][0] + o2.x) * linv, (O[s][dt][1] + o2.y) * linv),
                               cvtpk2((O[s][dt][2] + o2.z) * linv, (O[s][dt][3] + o2.w) * linv));
            }
        }
    }
}

// ---------------- launch ----------------
extern "C" void kernel_launch(void* const* d_in, const int* in_sizes, int n_in,
                              void* d_out, int out_size, void* d_ws, size_t ws_size,
                              hipStream_t stream)
{
    (void)in_sizes; (void)n_in; (void)out_size; (void)ws_size;
    const float* x   = (const float*)d_in[0];
    const float* Wq  = (const float*)d_in[1];
    const float* bq  = (const float*)d_in[2];
    const float* Wk  = (const float*)d_in[3];
    const float* bk  = (const float*)d_in[4];
    const float* Wv  = (const float*)d_in[5];
    const float* bv  = (const float*)d_in[6];
    const float* Wo  = (const float*)d_in[7];
    const float* bo  = (const float*)d_in[8];
    const float* Wqs = (const float*)d_in[9];
    const float* bqs = (const float*)d_in[10];
    const float* Wks = (const float*)d_in[11];
    const float* bks = (const float*)d_in[12];
    const float* Wvs = (const float*)d_in[13];
    const float* bvs = (const float*)d_in[14];
    const float* temp = (const float*)d_in[15];

    char* ws = (char*)d_ws;
    u16* xb  = (u16*)(ws);                  // 8 MB
    u16* Wqb = (u16*)(ws + 8388608);        // 2 MB
    u16* Wkb = (u16*)(ws + 10485760);       // 2 MB
    u16* Wvb = (u16*)(ws + 12582912);       // 2 MB
    u16* Wob = (u16*)(ws + 14680064);       // 2 MB
    u16* qeb = (u16*)(ws + 16777216);       // 12 MB [B,H,T,96]
    u16* keb = (u16*)(ws + 29360128);       // 12 MB
    u16* vTb = (u16*)(ws + 41943040);       // 8 MB  [B,H,64,T]
    float4* k3b = (float4*)(ws + 50331648); // 1 MB  [B*H*T]
    float4* v3b = (float4*)(ws + 51380224); // 1 MB
    u16* aob = (u16*)(ws + 52428800);       // 8 MB  [B,T,D]

    cast_all_kernel<<<8192, 256, 0, stream>>>(x, Wq, Wk, Wv, Wo, xb, Wqb, Wkb, Wvb, Wob);
    gemm_qkv_kernel<<<1536, 256, 0, stream>>>(
        xb, Wqb, Wkb, Wvb, bq, bk, bv, Wqs, bqs, Wks, bks, Wvs, bvs, temp,
        qeb, keb, vTb, k3b, v3b);
    finish_ext_kernel<<<256, 256, 0, stream>>>(k3b, v3b, keb);
    attn_kernel<<<512, 512, 0, stream>>>(qeb, keb, vTb, aob);
    gemm_out_kernel<<<512, 256, 0, stream>>>(aob, Wob, bo, (float*)d_out);
}